// Round 13
// baseline (203.989 us; speedup 1.0000x reference)
//
#include <hip/hip_runtime.h>
#include <hip/hip_bf16.h>
#include <stdint.h>

// Problem constants
#define MPTS  524288      // M per batch
#define NB    2           // N
#define CCH   80          // C
#define HWDIM 64          // H = W
#define HID   64
#define NPTS  (NB * MPTS) // 2^20

typedef _Float16 f16x2 __attribute__((ext_vector_type(2)));
typedef _Float16 f16x8 __attribute__((ext_vector_type(8)));
typedef float    f32x4 __attribute__((ext_vector_type(4)));

union FragH { uint4 q; f16x8 v; f16x2 h2[4]; unsigned d[4]; _Float16 h[8]; };
union PkU   { f16x2 v; unsigned u; };

// v_pk_fma_f16: acc.lo += a.lo*b.lo ; acc.hi += a.hi*b.hi  (1 VALU op, 2 MACs)
__device__ __forceinline__ void pk_fma(unsigned& acc, unsigned a, unsigned b) {
    asm volatile("v_pk_fma_f16 %0, %1, %2, %0" : "+v"(acc) : "v"(a), "v"(b));
}
__device__ __forceinline__ unsigned pk_relu(unsigned a) {
    unsigned r;
    asm volatile("v_pk_max_f16 %0, %1, %2" : "=v"(r) : "v"(a), "v"(0u));
    return r;
}

// ---------------------------------------------------------------------------
// Pre-kernel: planesW[np][y][x][64] fp16 = texel(80ch fp32) @ W1_p(80x64).
__global__ void precompute_planesW(const float* __restrict__ planes,
                                   const float* __restrict__ W1,
                                   unsigned short* __restrict__ planesW) {
    __shared__ float tA[CCH * 64];   // [c][px]
    __shared__ float tW[CCH * 64];   // [c][nn]
    int b  = blockIdx.x;
    int np = b >> 6, y = b & 63;
    int p  = np % 3;
    int t  = threadIdx.x;
    for (int i = t; i < CCH * 64; i += 256) {
        int c = i >> 6, x = i & 63;
        tA[i] = planes[((size_t)np * CCH + c) * 4096 + y * 64 + x];
        tW[i] = W1[(p * CCH + c) * HID + x];
    }
    __syncthreads();
    int px = t >> 2;
    int n0 = (t & 3) * 16;
    float acc[16];
    #pragma unroll
    for (int i = 0; i < 16; ++i) acc[i] = 0.0f;
    for (int c = 0; c < CCH; ++c) {
        float a = tA[c * 64 + px];
        #pragma unroll
        for (int i = 0; i < 16; ++i) acc[i] += a * tW[c * 64 + n0 + i];
    }
    unsigned short* dst = planesW + (((size_t)np * 4096) + y * 64 + px) * HID + n0;
    #pragma unroll
    for (int i = 0; i < 16; ++i) {
        union { _Float16 h; unsigned short u; } cv;
        cv.h = (_Float16)acc[i];
        dst[i] = cv.u;
    }
}

// ---------------------------------------------------------------------------
// Pre-kernel: W2, W3 (64x64) fp16 MFMA B-fragment order (proven layout).
__global__ void pack_weights23(const float* __restrict__ W2,
                               const float* __restrict__ W3,
                               unsigned short* __restrict__ wpack) {
    int e = blockIdx.x * 256 + threadIdx.x;   // 0..8191
    const float* W = (e < 4096) ? W2 : W3;
    int q  = e & 4095;
    int j  = q & 7;
    int l  = (q >> 3) & 63;
    int nt = (q >> 9) & 3;
    int kb = q >> 11;
    int k  = kb * 32 + ((l >> 4) << 3) + j;
    int nn = nt * 16 + (l & 15);
    union { _Float16 h; unsigned short u; } cv;
    cv.h = (_Float16)W[k * HID + nn];
    wpack[e] = cv.u;
}

// ---------------------------------------------------------------------------
// Main fused kernel: 512 threads = 8 waves, 128 points per block.
// No sSet (per-lane setup recompute, proven time-neutral r5->r6); LDS ~35.6 KB
// -> 4 blocks/CU = 32 waves/CU. T14 staging split: sW23 loads at top, LDS
// writes after phase B.
__global__ __launch_bounds__(512, 8) void fused_kernel(
        const unsigned short* __restrict__ planesW,
        const float* __restrict__ coords,
        const unsigned short* __restrict__ wpack,
        const float* __restrict__ b1, const float* __restrict__ b2,
        const float* __restrict__ b3, const float* __restrict__ W4,
        const float* __restrict__ b4, float* __restrict__ out) {

    __shared__ __align__(16) unsigned short sH[8 * 16 * 72]; // per-wave H tiles (18.4 KB)
    __shared__ __align__(16) unsigned short sW23[8192];      // W2|W3 fragments (16 KB)
    __shared__ float sBias[200];                             // b2[0:64) b3[64:128) W4[128:192) b4[192]

    int t    = threadIdx.x;
    int wave = t >> 6, lane = t & 63;
    int ptbase = blockIdx.x * 128 + wave * 16;

    unsigned short* hw = sH + wave * (16 * 72);
    _Float16* hwh = (_Float16*)hw;

    // ---------- T14 stage-issue: global loads now, LDS writes after phase B -
    uint4 st0, st1;
    {
        const uint4* g = (const uint4*)wpack;
        st0 = g[t];
        st1 = g[t + 512];
    }
    float br = 0.0f;
    if (t < 64)        br = b2[t];
    else if (t < 128)  br = b3[t - 64];
    else if (t < 192)  br = W4[t - 128];
    else if (t == 192) br = b4[0];

    // ---------- Phase B: per-lane setup + gather + layer-1 (pk_fma) --------
    {
        int sub = lane & 7;                  // 8-dim octet
        int ptg = lane >> 3;                 // point group

        unsigned bp0, bp1, bp2, bp3;
        {
            const float4* bpp = (const float4*)(b1 + sub * 8);
            float4 v0 = bpp[0], v1 = bpp[1];
            PkU pk;
            pk.v = f16x2{(_Float16)v0.x, (_Float16)v0.y}; bp0 = pk.u;
            pk.v = f16x2{(_Float16)v0.z, (_Float16)v0.w}; bp1 = pk.u;
            pk.v = f16x2{(_Float16)v1.x, (_Float16)v1.y}; bp2 = pk.u;
            pk.v = f16x2{(_Float16)v1.z, (_Float16)v1.w}; bp3 = pk.u;
        }
        const unsigned short* pw = planesW + sub * 8;

        // Per-plane bilinear setup -> named offsets + packed f16 splat weights.
        #define SETUP(GX, GY, PBASE, OA, OB, OC, OD, WA, WB, WC, WD)              \
        {   float fx = ((GX) + 1.0f) * 32.0f - 0.5f;                              \
            float fy = ((GY) + 1.0f) * 32.0f - 0.5f;                              \
            float xf = floorf(fx), yf = floorf(fy);                               \
            float wx = fx - xf,    wy = fy - yf;                                  \
            int x0 = (int)xf, y0 = (int)yf, x1 = x0 + 1, y1 = y0 + 1;             \
            float vx0 = (x0 >= 0 && x0 < 64) ? 1.0f : 0.0f;                       \
            float vx1 = (x1 >= 0 && x1 < 64) ? 1.0f : 0.0f;                       \
            float vy0 = (y0 >= 0 && y0 < 64) ? 1.0f : 0.0f;                       \
            float vy1 = (y1 >= 0 && y1 < 64) ? 1.0f : 0.0f;                       \
            int cx0 = min(max(x0, 0), 63), cx1 = min(max(x1, 0), 63);             \
            int cy0 = min(max(y0, 0), 63), cy1 = min(max(y1, 0), 63);             \
            PkU pk; _Float16 hh;                                                  \
            hh = (_Float16)((1.0f - wx) * (1.0f - wy) * vx0 * vy0);               \
            pk.v = f16x2{hh, hh}; WA = pk.u;                                      \
            hh = (_Float16)(wx * (1.0f - wy) * vx1 * vy0);                        \
            pk.v = f16x2{hh, hh}; WB = pk.u;                                      \
            hh = (_Float16)((1.0f - wx) * wy * vx0 * vy1);                        \
            pk.v = f16x2{hh, hh}; WC = pk.u;                                      \
            hh = (_Float16)(wx * wy * vx1 * vy1);                                 \
            pk.v = f16x2{hh, hh}; WD = pk.u;                                      \
            OA = (unsigned)(((PBASE) + (cy0 << 6) + cx0) * HID);                  \
            OB = (unsigned)(((PBASE) + (cy0 << 6) + cx1) * HID);                  \
            OC = (unsigned)(((PBASE) + (cy1 << 6) + cx0) * HID);                  \
            OD = (unsigned)(((PBASE) + (cy1 << 6) + cx1) * HID); }

        auto do_round = [&](int pt) {
            int mypt = ptbase + pt;
            int n    = mypt >> 19;               // MPTS = 2^19
            const float* cp = coords + (size_t)mypt * 3;
            float c0 = cp[0], c1 = cp[1], c2 = cp[2];
            int base0 = n * 3 * 4096;

            unsigned oA0, oA1, oA2, oA3, wA0, wA1, wA2, wA3;
            unsigned oB0, oB1, oB2, oB3, wB0, wB1, wB2, wB3;
            unsigned oC0, oC1, oC2, oC3, wC0, wC1, wC2, wC3;
            SETUP(c0, c1, base0,        oA0, oA1, oA2, oA3, wA0, wA1, wA2, wA3)
            SETUP(c0, c2, base0 + 4096, oB0, oB1, oB2, oB3, wB0, wB1, wB2, wB3)
            SETUP(c2, c1, base0 + 8192, oC0, oC1, oC2, oC3, wC0, wC1, wC2, wC3)

            FragH u0, u1, u2, u3, u4, u5, u6, u7, u8, u9, u10, u11;
            u0.q  = *(const uint4*)(pw + oA0);
            u1.q  = *(const uint4*)(pw + oA1);
            u2.q  = *(const uint4*)(pw + oA2);
            u3.q  = *(const uint4*)(pw + oA3);
            u4.q  = *(const uint4*)(pw + oB0);
            u5.q  = *(const uint4*)(pw + oB1);
            u6.q  = *(const uint4*)(pw + oB2);
            u7.q  = *(const uint4*)(pw + oB3);
            u8.q  = *(const uint4*)(pw + oC0);
            u9.q  = *(const uint4*)(pw + oC1);
            u10.q = *(const uint4*)(pw + oC2);
            u11.q = *(const uint4*)(pw + oC3);

            unsigned a0 = bp0, a1 = bp1, a2 = bp2, a3 = bp3;

            #define TEXEL(T, WB_) { pk_fma(a0, T.d[0], WB_); pk_fma(a1, T.d[1], WB_); \
                                    pk_fma(a2, T.d[2], WB_); pk_fma(a3, T.d[3], WB_); }
            TEXEL(u0,  wA0) TEXEL(u1,  wA1) TEXEL(u2,  wA2) TEXEL(u3,  wA3)
            TEXEL(u4,  wB0) TEXEL(u5,  wB1) TEXEL(u6,  wB2) TEXEL(u7,  wB3)
            TEXEL(u8,  wC0) TEXEL(u9,  wC1) TEXEL(u10, wC2) TEXEL(u11, wC3)
            #undef TEXEL

            uint4 hv;
            hv.x = pk_relu(a0); hv.y = pk_relu(a1);
            hv.z = pk_relu(a2); hv.w = pk_relu(a3);
            *(uint4*)(hwh + pt * 72 + sub * 8) = hv;
        };
        do_round(ptg);
        do_round(8 + ptg);
        #undef SETUP
    }

    // ---------- T14 stage-write + the ONLY block barrier -------------------
    {
        uint4* s = (uint4*)sW23;
        s[t]       = st0;
        s[t + 512] = st1;
        if (t <= 192) sBias[t] = br;
    }
    __syncthreads();

    // ---------- Layer 2: K=64, A from LDS, B from LDS ----------------------
    int row  = lane & 15;
    int kgrp = lane >> 4;
    f32x4 acc2[4] = {{0,0,0,0},{0,0,0,0},{0,0,0,0},{0,0,0,0}};
    #pragma unroll
    for (int kk = 0; kk < 2; ++kk) {
        FragH au;
        au.q = *(const uint4*)(hw + row * 72 + kk * 32 + kgrp * 8);
        #pragma unroll
        for (int nt = 0; nt < 4; ++nt) {
            FragH bu;
            bu.q = *(const uint4*)(sW23 + (kk * 4 + nt) * 512 + lane * 8);
            acc2[nt] = __builtin_amdgcn_mfma_f32_16x16x32_f16(au.v, bu.v, acc2[nt], 0, 0, 0);
        }
    }

    // Epilogue 2 (biases from LDS; wave-private tile, no block barrier)
    #pragma unroll
    for (int nt = 0; nt < 4; ++nt) {
        float bb = sBias[nt * 16 + row];
        #pragma unroll
        for (int r = 0; r < 4; ++r) {
            float h = fmaxf(acc2[nt][r] + bb, 0.0f);
            hwh[(kgrp * 4 + r) * 72 + nt * 16 + row] = (_Float16)h;
        }
    }

    // ---------- Layer 3: K=64, B from LDS -----------------------------------
    f32x4 acc3[4] = {{0,0,0,0},{0,0,0,0},{0,0,0,0},{0,0,0,0}};
    #pragma unroll
    for (int kk = 0; kk < 2; ++kk) {
        FragH au;
        au.q = *(const uint4*)(hw + row * 72 + kk * 32 + kgrp * 8);
        #pragma unroll
        for (int nt = 0; nt < 4; ++nt) {
            FragH bu;
            bu.q = *(const uint4*)(sW23 + 4096 + (kk * 4 + nt) * 512 + lane * 8);
            acc3[nt] = __builtin_amdgcn_mfma_f32_16x16x32_f16(au.v, bu.v, acc3[nt], 0, 0, 0);
        }
    }

    // ---------- Layer 4: 64 -> 1, fp32 VALU + 16-lane reduce ----------------
    float part[4] = {0.f, 0.f, 0.f, 0.f};
    #pragma unroll
    for (int nt = 0; nt < 4; ++nt) {
        float bb  = sBias[64 + nt * 16 + row];
        float w4v = sBias[128 + nt * 16 + row];
        #pragma unroll
        for (int r = 0; r < 4; ++r) {
            float h = fmaxf(acc3[nt][r] + bb, 0.0f);
            part[r] += h * w4v;
        }
    }
    #pragma unroll
    for (int r = 0; r < 4; ++r) {
        #pragma unroll
        for (int off = 1; off < 16; off <<= 1)
            part[r] += __shfl_xor(part[r], off);
    }
    if (row == 0) {
        float bias4 = sBias[192];
        float4 o;
        o.x = part[0] + bias4; o.y = part[1] + bias4;
        o.z = part[2] + bias4; o.w = part[3] + bias4;
        *(float4*)(out + ptbase + kgrp * 4) = o;
    }
}

// ---------------------------------------------------------------------------
extern "C" void kernel_launch(void* const* d_in, const int* in_sizes, int n_in,
                              void* d_out, int out_size, void* d_ws, size_t ws_size,
                              hipStream_t stream) {
    const float* planes = (const float*)d_in[0];
    const float* coords = (const float*)d_in[1];
    const float* W1 = (const float*)d_in[2];
    const float* b1 = (const float*)d_in[3];
    const float* W2 = (const float*)d_in[4];
    const float* b2 = (const float*)d_in[5];
    const float* W3 = (const float*)d_in[6];
    const float* b3 = (const float*)d_in[7];
    const float* W4 = (const float*)d_in[8];
    const float* b4 = (const float*)d_in[9];
    float* out = (float*)d_out;

    // Workspace: planesW fp16 (3,145,728 B) | wpack fp16 (16,384 B)
    unsigned short* planesW = (unsigned short*)d_ws;
    unsigned short* wpack   = (unsigned short*)((char*)d_ws + 3145728);

    hipLaunchKernelGGL(precompute_planesW, dim3(NB * 3 * HWDIM), dim3(256), 0, stream,
                       planes, W1, planesW);
    hipLaunchKernelGGL(pack_weights23, dim3(32), dim3(256), 0, stream,
                       W2, W3, wpack);

    int nblocks = NPTS / 128;   // 8192
    hipLaunchKernelGGL(fused_kernel, dim3(nblocks), dim3(512), 0, stream,
                       planesW, coords, wpack, b1, b2, b3, W4, b4, out);
}

// Round 14
// 134.689 us; speedup vs baseline: 1.5145x; 1.5145x over previous
//
#include <hip/hip_runtime.h>
#include <hip/hip_bf16.h>
#include <stdint.h>

// Problem constants
#define MPTS  524288      // M per batch
#define NB    2           // N
#define CCH   80          // C
#define HWDIM 64          // H = W
#define HID   64
#define NPTS  (NB * MPTS) // 2^20

typedef _Float16 f16x2 __attribute__((ext_vector_type(2)));
typedef _Float16 f16x8 __attribute__((ext_vector_type(8)));
typedef float    f32x4 __attribute__((ext_vector_type(4)));

union FragH { uint4 q; f16x8 v; f16x2 h2[4]; unsigned d[4]; _Float16 h[8]; };
union PkU   { f16x2 v; unsigned u; };

// v_pk_fma_f16: acc.lo += a.lo*b.lo ; acc.hi += a.hi*b.hi  (1 VALU op, 2 MACs)
__device__ __forceinline__ void pk_fma(unsigned& acc, unsigned a, unsigned b) {
    asm volatile("v_pk_fma_f16 %0, %1, %2, %0" : "+v"(acc) : "v"(a), "v"(b));
}
__device__ __forceinline__ unsigned pk_relu(unsigned a) {
    unsigned r;
    asm volatile("v_pk_max_f16 %0, %1, %2" : "=v"(r) : "v"(a), "v"(0u));
    return r;
}
// Splat lo/hi fp16 of a u32 into both halves (v_perm_b32, exact bit copy).
__device__ __forceinline__ unsigned splat_lo(unsigned w) {
    return __builtin_amdgcn_perm(w, w, 0x05040504u);   // bytes (1,0,1,0)
}
__device__ __forceinline__ unsigned splat_hi(unsigned w) {
    return __builtin_amdgcn_perm(w, w, 0x07060706u);   // bytes (3,2,3,2)
}

// ---------------------------------------------------------------------------
// Pre-kernel: planesW[np][y][x][64] fp16 = texel(80ch fp32) @ W1_p(80x64).
__global__ void precompute_planesW(const float* __restrict__ planes,
                                   const float* __restrict__ W1,
                                   unsigned short* __restrict__ planesW) {
    __shared__ float tA[CCH * 64];   // [c][px]
    __shared__ float tW[CCH * 64];   // [c][nn]
    int b  = blockIdx.x;
    int np = b >> 6, y = b & 63;
    int p  = np % 3;
    int t  = threadIdx.x;
    for (int i = t; i < CCH * 64; i += 256) {
        int c = i >> 6, x = i & 63;
        tA[i] = planes[((size_t)np * CCH + c) * 4096 + y * 64 + x];
        tW[i] = W1[(p * CCH + c) * HID + x];
    }
    __syncthreads();
    int px = t >> 2;
    int n0 = (t & 3) * 16;
    float acc[16];
    #pragma unroll
    for (int i = 0; i < 16; ++i) acc[i] = 0.0f;
    for (int c = 0; c < CCH; ++c) {
        float a = tA[c * 64 + px];
        #pragma unroll
        for (int i = 0; i < 16; ++i) acc[i] += a * tW[c * 64 + n0 + i];
    }
    unsigned short* dst = planesW + (((size_t)np * 4096) + y * 64 + px) * HID + n0;
    #pragma unroll
    for (int i = 0; i < 16; ++i) {
        union { _Float16 h; unsigned short u; } cv;
        cv.h = (_Float16)acc[i];
        dst[i] = cv.u;
    }
}

// ---------------------------------------------------------------------------
// Pre-kernel: W2, W3 (64x64) fp16 MFMA B-fragment order (proven layout).
__global__ void pack_weights23(const float* __restrict__ W2,
                               const float* __restrict__ W3,
                               unsigned short* __restrict__ wpack) {
    int e = blockIdx.x * 256 + threadIdx.x;   // 0..8191
    const float* W = (e < 4096) ? W2 : W3;
    int q  = e & 4095;
    int j  = q & 7;
    int l  = (q >> 3) & 63;
    int nt = (q >> 9) & 3;
    int kb = q >> 11;
    int k  = kb * 32 + ((l >> 4) << 3) + j;
    int nn = nt * 16 + (l & 15);
    union { _Float16 h; unsigned short u; } cv;
    cv.h = (_Float16)W[k * HID + nn];
    wpack[e] = cv.u;
}

// ---------------------------------------------------------------------------
// Main fused kernel: 512 threads = 8 waves, 128 points per block.
// Compact sSet (4.6 KB): LDS 40224 B -> 4 blocks/CU = 32 waves/CU, with
// W2+W3 still in LDS. Phase-B live set matches r12 (~40-50 VGPR, no spill).
__global__ __launch_bounds__(512, 8) void fused_kernel(
        const unsigned short* __restrict__ planesW,
        const float* __restrict__ coords,
        const unsigned short* __restrict__ wpack,
        const float* __restrict__ b1, const float* __restrict__ b2,
        const float* __restrict__ b3, const float* __restrict__ W4,
        const float* __restrict__ b4, float* __restrict__ out) {

    __shared__ __align__(16) unsigned short sH[8 * 16 * 72]; // 18432 B
    __shared__ unsigned sOff[128][3];                        // 1536 B: byte-off + flags
    __shared__ unsigned sWgt[128][3][2];                     // 3072 B: {w00,w01},{w10,w11} fp16 pairs
    __shared__ __align__(16) unsigned short sW23[8192];      // 16384 B
    __shared__ float sBias[200];                             // 800 B

    int t    = threadIdx.x;
    int wave = t >> 6, lane = t & 63;
    int ptbase = blockIdx.x * 128 + wave * 16;

    unsigned short* hw = sH + wave * (16 * 72);
    _Float16* hwh = (_Float16*)hw;

    // ---------- Stage W2/W3 fragments + biases into LDS --------------------
    {
        const uint4* g = (const uint4*)wpack;
        uint4* s = (uint4*)sW23;
        s[t]       = g[t];          // 1024 uint4 over 512 threads
        s[t + 512] = g[t + 512];
        if (t < 64)        sBias[t] = b2[t];
        else if (t < 128)  sBias[t] = b3[t - 64];
        else if (t < 192)  sBias[t] = W4[t - 128];
        else if (t == 192) sBias[192] = b4[0];
    }

    // ---------- Sub-phase A: per-point bilinear setup, compact records -----
    if (t < 384) {
        int i  = t & 127;                    // local point
        int p  = t >> 7;                     // plane
        int mypt = blockIdx.x * 128 + i;
        int n    = mypt >> 19;               // MPTS = 2^19
        const float* cp = coords + (size_t)mypt * 3;
        float c0 = cp[0], c1 = cp[1], c2 = cp[2];
        float gx = (p == 2) ? c2 : c0;       // p0:(x,y) p1:(x,z) p2:(z,y)
        float gy = (p == 1) ? c2 : c1;
        float fx = (gx + 1.0f) * 32.0f - 0.5f;
        float fy = (gy + 1.0f) * 32.0f - 0.5f;
        float xf = floorf(fx), yf = floorf(fy);
        float wx = fx - xf,    wy = fy - yf;
        int x0 = (int)xf, y0 = (int)yf, x1 = x0 + 1, y1 = y0 + 1;
        float vx0 = (x0 >= 0 && x0 < 64) ? 1.0f : 0.0f;
        float vx1 = (x1 >= 0 && x1 < 64) ? 1.0f : 0.0f;
        float vy0 = (y0 >= 0 && y0 < 64) ? 1.0f : 0.0f;
        float vy1 = (y1 >= 0 && y1 < 64) ? 1.0f : 0.0f;
        int cx0 = min(max(x0, 0), 63), cx1 = min(max(x1, 0), 63);
        int cy0 = min(max(y0, 0), 63), cy1 = min(max(y1, 0), 63);
        _Float16 h00 = (_Float16)((1.0f - wx) * (1.0f - wy) * vx0 * vy0);
        _Float16 h01 = (_Float16)(wx * (1.0f - wy) * vx1 * vy0);
        _Float16 h10 = (_Float16)((1.0f - wx) * wy * vx0 * vy1);
        _Float16 h11 = (_Float16)(wx * wy * vx1 * vy1);
        int base = (n * 3 + p) * 4096;
        unsigned o00b = (unsigned)(((base + (cy0 << 6) + cx0) * HID) * 2); // bytes, <2^22
        unsigned offv = o00b
                      | ((cx1 > cx0) ? (1u << 30) : 0u)
                      | ((cy1 > cy0) ? (1u << 31) : 0u);
        PkU p01; p01.v = f16x2{h00, h01};
        PkU p23; p23.v = f16x2{h10, h11};
        sOff[i][p]    = offv;
        sWgt[i][p][0] = p01.u;
        sWgt[i][p][1] = p23.u;
    }
    __syncthreads();   // the ONLY block-wide barrier

    // ---------- Sub-phase B: gather + layer-1 accumulate (pk_fma) ----------
    {
        int sub = lane & 7;                  // 8-dim octet
        int ptg = lane >> 3;                 // point group

        unsigned bp0, bp1, bp2, bp3;
        {
            const float4* bpp = (const float4*)(b1 + sub * 8);
            float4 v0 = bpp[0], v1 = bpp[1];
            PkU pk;
            pk.v = f16x2{(_Float16)v0.x, (_Float16)v0.y}; bp0 = pk.u;
            pk.v = f16x2{(_Float16)v0.z, (_Float16)v0.w}; bp1 = pk.u;
            pk.v = f16x2{(_Float16)v1.x, (_Float16)v1.y}; bp2 = pk.u;
            pk.v = f16x2{(_Float16)v1.z, (_Float16)v1.w}; bp3 = pk.u;
        }
        const char* pwB = (const char*)planesW + sub * 16;

        auto do_round = [&](int pt) {
            int pl = wave * 16 + pt;
            // Reconstruct 12 corner byte-offsets + 12 splat weights.
            unsigned ovA = sOff[pl][0], ovB = sOff[pl][1], ovC = sOff[pl][2];
            unsigned wpA0 = sWgt[pl][0][0], wpA1 = sWgt[pl][0][1];
            unsigned wpB0 = sWgt[pl][1][0], wpB1 = sWgt[pl][1][1];
            unsigned wpC0 = sWgt[pl][2][0], wpC1 = sWgt[pl][2][1];

            #define RECON(OV, O00, O01, O10, O11)                                 \
                unsigned O00 = (OV) & 0x00FFFFFFu;                                \
                unsigned O01 = O00 + (((OV) >> 30) & 1u ? 128u : 0u);             \
                unsigned dY_##O00 = ((OV) >> 31) ? 8192u : 0u;                    \
                unsigned O10 = O00 + dY_##O00;                                    \
                unsigned O11 = O01 + dY_##O00;
            RECON(ovA, oA0, oA1, oA2, oA3)
            RECON(ovB, oB0, oB1, oB2, oB3)
            RECON(ovC, oC0, oC1, oC2, oC3)
            #undef RECON

            FragH u0, u1, u2, u3, u4, u5, u6, u7, u8, u9, u10, u11;
            u0.q  = *(const uint4*)(pwB + oA0);
            u1.q  = *(const uint4*)(pwB + oA1);
            u2.q  = *(const uint4*)(pwB + oA2);
            u3.q  = *(const uint4*)(pwB + oA3);
            u4.q  = *(const uint4*)(pwB + oB0);
            u5.q  = *(const uint4*)(pwB + oB1);
            u6.q  = *(const uint4*)(pwB + oB2);
            u7.q  = *(const uint4*)(pwB + oB3);
            u8.q  = *(const uint4*)(pwB + oC0);
            u9.q  = *(const uint4*)(pwB + oC1);
            u10.q = *(const uint4*)(pwB + oC2);
            u11.q = *(const uint4*)(pwB + oC3);

            unsigned a0 = bp0, a1 = bp1, a2 = bp2, a3 = bp3;

            #define TEXEL(T, WB_) { pk_fma(a0, T.d[0], WB_); pk_fma(a1, T.d[1], WB_); \
                                    pk_fma(a2, T.d[2], WB_); pk_fma(a3, T.d[3], WB_); }
            TEXEL(u0,  splat_lo(wpA0)) TEXEL(u1,  splat_hi(wpA0))
            TEXEL(u2,  splat_lo(wpA1)) TEXEL(u3,  splat_hi(wpA1))
            TEXEL(u4,  splat_lo(wpB0)) TEXEL(u5,  splat_hi(wpB0))
            TEXEL(u6,  splat_lo(wpB1)) TEXEL(u7,  splat_hi(wpB1))
            TEXEL(u8,  splat_lo(wpC0)) TEXEL(u9,  splat_hi(wpC0))
            TEXEL(u10, splat_lo(wpC1)) TEXEL(u11, splat_hi(wpC1))
            #undef TEXEL

            uint4 hv;
            hv.x = pk_relu(a0); hv.y = pk_relu(a1);
            hv.z = pk_relu(a2); hv.w = pk_relu(a3);
            *(uint4*)(hwh + pt * 72 + sub * 8) = hv;
        };
        do_round(ptg);
        do_round(8 + ptg);
    }
    // No block barrier: H tile is wave-private; compiler orders LDS hazards.

    // ---------- Layer 2: K=64, A from LDS, B from LDS ----------------------
    int row  = lane & 15;
    int kgrp = lane >> 4;
    f32x4 acc2[4] = {{0,0,0,0},{0,0,0,0},{0,0,0,0},{0,0,0,0}};
    #pragma unroll
    for (int kk = 0; kk < 2; ++kk) {
        FragH au;
        au.q = *(const uint4*)(hw + row * 72 + kk * 32 + kgrp * 8);
        #pragma unroll
        for (int nt = 0; nt < 4; ++nt) {
            FragH bu;
            bu.q = *(const uint4*)(sW23 + (kk * 4 + nt) * 512 + lane * 8);
            acc2[nt] = __builtin_amdgcn_mfma_f32_16x16x32_f16(au.v, bu.v, acc2[nt], 0, 0, 0);
        }
    }

    // Epilogue 2 (biases from LDS; wave-private tile, no block barrier)
    #pragma unroll
    for (int nt = 0; nt < 4; ++nt) {
        float bb = sBias[nt * 16 + row];
        #pragma unroll
        for (int r = 0; r < 4; ++r) {
            float h = fmaxf(acc2[nt][r] + bb, 0.0f);
            hwh[(kgrp * 4 + r) * 72 + nt * 16 + row] = (_Float16)h;
        }
    }

    // ---------- Layer 3: K=64, B from LDS -----------------------------------
    f32x4 acc3[4] = {{0,0,0,0},{0,0,0,0},{0,0,0,0},{0,0,0,0}};
    #pragma unroll
    for (int kk = 0; kk < 2; ++kk) {
        FragH au;
        au.q = *(const uint4*)(hw + row * 72 + kk * 32 + kgrp * 8);
        #pragma unroll
        for (int nt = 0; nt < 4; ++nt) {
            FragH bu;
            bu.q = *(const uint4*)(sW23 + 4096 + (kk * 4 + nt) * 512 + lane * 8);
            acc3[nt] = __builtin_amdgcn_mfma_f32_16x16x32_f16(au.v, bu.v, acc3[nt], 0, 0, 0);
        }
    }

    // ---------- Layer 4: 64 -> 1, fp32 VALU + 16-lane reduce ----------------
    float part[4] = {0.f, 0.f, 0.f, 0.f};
    #pragma unroll
    for (int nt = 0; nt < 4; ++nt) {
        float bb  = sBias[64 + nt * 16 + row];
        float w4v = sBias[128 + nt * 16 + row];
        #pragma unroll
        for (int r = 0; r < 4; ++r) {
            float h = fmaxf(acc3[nt][r] + bb, 0.0f);
            part[r] += h * w4v;
        }
    }
    #pragma unroll
    for (int r = 0; r < 4; ++r) {
        #pragma unroll
        for (int off = 1; off < 16; off <<= 1)
            part[r] += __shfl_xor(part[r], off);
    }
    if (row == 0) {
        float bias4 = sBias[192];
        float4 o;
        o.x = part[0] + bias4; o.y = part[1] + bias4;
        o.z = part[2] + bias4; o.w = part[3] + bias4;
        *(float4*)(out + ptbase + kgrp * 4) = o;
    }
}

// ---------------------------------------------------------------------------
extern "C" void kernel_launch(void* const* d_in, const int* in_sizes, int n_in,
                              void* d_out, int out_size, void* d_ws, size_t ws_size,
                              hipStream_t stream) {
    const float* planes = (const float*)d_in[0];
    const float* coords = (const float*)d_in[1];
    const float* W1 = (const float*)d_in[2];
    const float* b1 = (const float*)d_in[3];
    const float* W2 = (const float*)d_in[4];
    const float* b2 = (const float*)d_in[5];
    const float* W3 = (const float*)d_in[6];
    const float* b3 = (const float*)d_in[7];
    const float* W4 = (const float*)d_in[8];
    const float* b4 = (const float*)d_in[9];
    float* out = (float*)d_out;

    // Workspace: planesW fp16 (3,145,728 B) | wpack fp16 (16,384 B)
    unsigned short* planesW = (unsigned short*)d_ws;
    unsigned short* wpack   = (unsigned short*)((char*)d_ws + 3145728);

    hipLaunchKernelGGL(precompute_planesW, dim3(NB * 3 * HWDIM), dim3(256), 0, stream,
                       planes, W1, planesW);
    hipLaunchKernelGGL(pack_weights23, dim3(32), dim3(256), 0, stream,
                       W2, W3, wpack);

    int nblocks = NPTS / 128;   // 8192
    hipLaunchKernelGGL(fused_kernel, dim3(nblocks), dim3(512), 0, stream,
                       planesW, coords, wpack, b1, b2, b3, W4, b4, out);
}

// Round 15
// 134.199 us; speedup vs baseline: 1.5201x; 1.0037x over previous
//
#include <hip/hip_runtime.h>
#include <hip/hip_bf16.h>
#include <stdint.h>

// Problem constants
#define MPTS  524288      // M per batch
#define NB    2           // N
#define CCH   80          // C
#define HWDIM 64          // H = W
#define HID   64
#define NPTS  (NB * MPTS) // 2^20

typedef _Float16 f16x2 __attribute__((ext_vector_type(2)));
typedef _Float16 f16x8 __attribute__((ext_vector_type(8)));
typedef float    f32x4 __attribute__((ext_vector_type(4)));

union FragH { uint4 q; f16x8 v; f16x2 h2[4]; unsigned d[4]; _Float16 h[8]; };
union PkU   { f16x2 v; unsigned u; };

// v_pk_fma_f16: acc.lo += a.lo*b.lo ; acc.hi += a.hi*b.hi  (1 VALU op, 2 MACs)
__device__ __forceinline__ void pk_fma(unsigned& acc, unsigned a, unsigned b) {
    asm volatile("v_pk_fma_f16 %0, %1, %2, %0" : "+v"(acc) : "v"(a), "v"(b));
}
__device__ __forceinline__ unsigned pk_relu(unsigned a) {
    unsigned r;
    asm volatile("v_pk_max_f16 %0, %1, %2" : "=v"(r) : "v"(a), "v"(0u));
    return r;
}
// Splat lo/hi fp16 of a u32 into both halves (v_perm_b32, exact bit copy).
__device__ __forceinline__ unsigned splat_lo(unsigned w) {
    return __builtin_amdgcn_perm(w, w, 0x05040504u);   // bytes (1,0,1,0)
}
__device__ __forceinline__ unsigned splat_hi(unsigned w) {
    return __builtin_amdgcn_perm(w, w, 0x07060706u);   // bytes (3,2,3,2)
}

// ---------------------------------------------------------------------------
// Pre-kernel: planesW[np][y][x][64] fp16 = texel(80ch fp32) @ W1_p(80x64).
__global__ void precompute_planesW(const float* __restrict__ planes,
                                   const float* __restrict__ W1,
                                   unsigned short* __restrict__ planesW) {
    __shared__ float tA[CCH * 64];   // [c][px]
    __shared__ float tW[CCH * 64];   // [c][nn]
    int b  = blockIdx.x;
    int np = b >> 6, y = b & 63;
    int p  = np % 3;
    int t  = threadIdx.x;
    for (int i = t; i < CCH * 64; i += 256) {
        int c = i >> 6, x = i & 63;
        tA[i] = planes[((size_t)np * CCH + c) * 4096 + y * 64 + x];
        tW[i] = W1[(p * CCH + c) * HID + x];
    }
    __syncthreads();
    int px = t >> 2;
    int n0 = (t & 3) * 16;
    float acc[16];
    #pragma unroll
    for (int i = 0; i < 16; ++i) acc[i] = 0.0f;
    for (int c = 0; c < CCH; ++c) {
        float a = tA[c * 64 + px];
        #pragma unroll
        for (int i = 0; i < 16; ++i) acc[i] += a * tW[c * 64 + n0 + i];
    }
    unsigned short* dst = planesW + (((size_t)np * 4096) + y * 64 + px) * HID + n0;
    #pragma unroll
    for (int i = 0; i < 16; ++i) {
        union { _Float16 h; unsigned short u; } cv;
        cv.h = (_Float16)acc[i];
        dst[i] = cv.u;
    }
}

// ---------------------------------------------------------------------------
// Pre-kernel: W2, W3 (64x64) fp16 MFMA B-fragment order (proven layout).
__global__ void pack_weights23(const float* __restrict__ W2,
                               const float* __restrict__ W3,
                               unsigned short* __restrict__ wpack) {
    int e = blockIdx.x * 256 + threadIdx.x;   // 0..8191
    const float* W = (e < 4096) ? W2 : W3;
    int q  = e & 4095;
    int j  = q & 7;
    int l  = (q >> 3) & 63;
    int nt = (q >> 9) & 3;
    int kb = q >> 11;
    int k  = kb * 32 + ((l >> 4) << 3) + j;
    int nn = nt * 16 + (l & 15);
    union { _Float16 h; unsigned short u; } cv;
    cv.h = (_Float16)W[k * HID + nn];
    wpack[e] = cv.u;
}

// ---------------------------------------------------------------------------
// Main fused kernel: 512 threads = 8 waves, 128 points per block.
// Compact sSet (4.6 KB) -> LDS 40448 B -> 4 blocks/CU. Single shared MFMA
// accumulator (16 AGPR, not 32) so arch+acc fits the 64-reg cap of (512,8).
__global__ __launch_bounds__(512, 8) void fused_kernel(
        const unsigned short* __restrict__ planesW,
        const float* __restrict__ coords,
        const unsigned short* __restrict__ wpack,
        const float* __restrict__ b1, const float* __restrict__ b2,
        const float* __restrict__ b3, const float* __restrict__ W4,
        const float* __restrict__ b4, float* __restrict__ out) {

    __shared__ __align__(16) unsigned short sH[8 * 16 * 72]; // 18432 B
    __shared__ unsigned sOff[128][3];                        // 1536 B: byte-off + flags
    __shared__ unsigned sWgt[128][3][2];                     // 3072 B: {w00,w01},{w10,w11} fp16 pairs
    __shared__ __align__(16) unsigned short sW23[8192];      // 16384 B
    __shared__ float sBias[200];                             // 800 B

    int t    = threadIdx.x;
    int wave = t >> 6, lane = t & 63;
    int ptbase = blockIdx.x * 128 + wave * 16;

    unsigned short* hw = sH + wave * (16 * 72);
    _Float16* hwh = (_Float16*)hw;

    // ---------- Stage W2/W3 fragments + biases into LDS --------------------
    {
        const uint4* g = (const uint4*)wpack;
        uint4* s = (uint4*)sW23;
        s[t]       = g[t];          // 1024 uint4 over 512 threads
        s[t + 512] = g[t + 512];
        if (t < 64)        sBias[t] = b2[t];
        else if (t < 128)  sBias[t] = b3[t - 64];
        else if (t < 192)  sBias[t] = W4[t - 128];
        else if (t == 192) sBias[192] = b4[0];
    }

    // ---------- Sub-phase A: per-point bilinear setup, compact records -----
    if (t < 384) {
        int i  = t & 127;                    // local point
        int p  = t >> 7;                     // plane
        int mypt = blockIdx.x * 128 + i;
        int n    = mypt >> 19;               // MPTS = 2^19
        const float* cp = coords + (size_t)mypt * 3;
        float c0 = cp[0], c1 = cp[1], c2 = cp[2];
        float gx = (p == 2) ? c2 : c0;       // p0:(x,y) p1:(x,z) p2:(z,y)
        float gy = (p == 1) ? c2 : c1;
        float fx = (gx + 1.0f) * 32.0f - 0.5f;
        float fy = (gy + 1.0f) * 32.0f - 0.5f;
        float xf = floorf(fx), yf = floorf(fy);
        float wx = fx - xf,    wy = fy - yf;
        int x0 = (int)xf, y0 = (int)yf, x1 = x0 + 1, y1 = y0 + 1;
        float vx0 = (x0 >= 0 && x0 < 64) ? 1.0f : 0.0f;
        float vx1 = (x1 >= 0 && x1 < 64) ? 1.0f : 0.0f;
        float vy0 = (y0 >= 0 && y0 < 64) ? 1.0f : 0.0f;
        float vy1 = (y1 >= 0 && y1 < 64) ? 1.0f : 0.0f;
        int cx0 = min(max(x0, 0), 63), cx1 = min(max(x1, 0), 63);
        int cy0 = min(max(y0, 0), 63), cy1 = min(max(y1, 0), 63);
        _Float16 h00 = (_Float16)((1.0f - wx) * (1.0f - wy) * vx0 * vy0);
        _Float16 h01 = (_Float16)(wx * (1.0f - wy) * vx1 * vy0);
        _Float16 h10 = (_Float16)((1.0f - wx) * wy * vx0 * vy1);
        _Float16 h11 = (_Float16)(wx * wy * vx1 * vy1);
        int base = (n * 3 + p) * 4096;
        unsigned o00b = (unsigned)(((base + (cy0 << 6) + cx0) * HID) * 2); // bytes, <2^22
        unsigned offv = o00b
                      | ((cx1 > cx0) ? (1u << 30) : 0u)
                      | ((cy1 > cy0) ? (1u << 31) : 0u);
        PkU p01; p01.v = f16x2{h00, h01};
        PkU p23; p23.v = f16x2{h10, h11};
        sOff[i][p]    = offv;
        sWgt[i][p][0] = p01.u;
        sWgt[i][p][1] = p23.u;
    }
    __syncthreads();   // the ONLY block-wide barrier

    // ---------- Sub-phase B: gather + layer-1 accumulate (pk_fma) ----------
    {
        int sub = lane & 7;                  // 8-dim octet
        int ptg = lane >> 3;                 // point group

        unsigned bp0, bp1, bp2, bp3;
        {
            const float4* bpp = (const float4*)(b1 + sub * 8);
            float4 v0 = bpp[0], v1 = bpp[1];
            PkU pk;
            pk.v = f16x2{(_Float16)v0.x, (_Float16)v0.y}; bp0 = pk.u;
            pk.v = f16x2{(_Float16)v0.z, (_Float16)v0.w}; bp1 = pk.u;
            pk.v = f16x2{(_Float16)v1.x, (_Float16)v1.y}; bp2 = pk.u;
            pk.v = f16x2{(_Float16)v1.z, (_Float16)v1.w}; bp3 = pk.u;
        }
        const char* pwB = (const char*)planesW + sub * 16;

        auto do_round = [&](int pt) {
            int pl = wave * 16 + pt;
            unsigned ovA = sOff[pl][0], ovB = sOff[pl][1], ovC = sOff[pl][2];
            unsigned wpA0 = sWgt[pl][0][0], wpA1 = sWgt[pl][0][1];
            unsigned wpB0 = sWgt[pl][1][0], wpB1 = sWgt[pl][1][1];
            unsigned wpC0 = sWgt[pl][2][0], wpC1 = sWgt[pl][2][1];

            #define RECON(OV, O00, O01, O10, O11)                                 \
                unsigned O00 = (OV) & 0x00FFFFFFu;                                \
                unsigned O01 = O00 + (((OV) >> 30) & 1u ? 128u : 0u);             \
                unsigned dY_##O00 = ((OV) >> 31) ? 8192u : 0u;                    \
                unsigned O10 = O00 + dY_##O00;                                    \
                unsigned O11 = O01 + dY_##O00;
            RECON(ovA, oA0, oA1, oA2, oA3)
            RECON(ovB, oB0, oB1, oB2, oB3)
            RECON(ovC, oC0, oC1, oC2, oC3)
            #undef RECON

            FragH u0, u1, u2, u3, u4, u5, u6, u7, u8, u9, u10, u11;
            u0.q  = *(const uint4*)(pwB + oA0);
            u1.q  = *(const uint4*)(pwB + oA1);
            u2.q  = *(const uint4*)(pwB + oA2);
            u3.q  = *(const uint4*)(pwB + oA3);
            u4.q  = *(const uint4*)(pwB + oB0);
            u5.q  = *(const uint4*)(pwB + oB1);
            u6.q  = *(const uint4*)(pwB + oB2);
            u7.q  = *(const uint4*)(pwB + oB3);
            u8.q  = *(const uint4*)(pwB + oC0);
            u9.q  = *(const uint4*)(pwB + oC1);
            u10.q = *(const uint4*)(pwB + oC2);
            u11.q = *(const uint4*)(pwB + oC3);

            unsigned a0 = bp0, a1 = bp1, a2 = bp2, a3 = bp3;

            #define TEXEL(T, WB_) { pk_fma(a0, T.d[0], WB_); pk_fma(a1, T.d[1], WB_); \
                                    pk_fma(a2, T.d[2], WB_); pk_fma(a3, T.d[3], WB_); }
            TEXEL(u0,  splat_lo(wpA0)) TEXEL(u1,  splat_hi(wpA0))
            TEXEL(u2,  splat_lo(wpA1)) TEXEL(u3,  splat_hi(wpA1))
            TEXEL(u4,  splat_lo(wpB0)) TEXEL(u5,  splat_hi(wpB0))
            TEXEL(u6,  splat_lo(wpB1)) TEXEL(u7,  splat_hi(wpB1))
            TEXEL(u8,  splat_lo(wpC0)) TEXEL(u9,  splat_hi(wpC0))
            TEXEL(u10, splat_lo(wpC1)) TEXEL(u11, splat_hi(wpC1))
            #undef TEXEL

            uint4 hv;
            hv.x = pk_relu(a0); hv.y = pk_relu(a1);
            hv.z = pk_relu(a2); hv.w = pk_relu(a3);
            *(uint4*)(hwh + pt * 72 + sub * 8) = hv;
        };
        do_round(ptg);
        do_round(8 + ptg);
    }
    // No block barrier: H tile is wave-private; compiler orders LDS hazards.

    // ---------- Layers 2 & 3 share ONE 16-AGPR accumulator -----------------
    int row  = lane & 15;
    int kgrp = lane >> 4;
    f32x4 acc[4];

    // Layer 2: K=64, A from LDS, B from LDS
    #pragma unroll
    for (int nt = 0; nt < 4; ++nt) acc[nt] = f32x4{0, 0, 0, 0};
    #pragma unroll
    for (int kk = 0; kk < 2; ++kk) {
        FragH au;
        au.q = *(const uint4*)(hw + row * 72 + kk * 32 + kgrp * 8);
        #pragma unroll
        for (int nt = 0; nt < 4; ++nt) {
            FragH bu;
            bu.q = *(const uint4*)(sW23 + (kk * 4 + nt) * 512 + lane * 8);
            acc[nt] = __builtin_amdgcn_mfma_f32_16x16x32_f16(au.v, bu.v, acc[nt], 0, 0, 0);
        }
    }

    // Epilogue 2 (biases from LDS; wave-private tile, no block barrier)
    #pragma unroll
    for (int nt = 0; nt < 4; ++nt) {
        float bb = sBias[nt * 16 + row];
        #pragma unroll
        for (int r = 0; r < 4; ++r) {
            float h = fmaxf(acc[nt][r] + bb, 0.0f);
            hwh[(kgrp * 4 + r) * 72 + nt * 16 + row] = (_Float16)h;
        }
    }
    __builtin_amdgcn_sched_barrier(0);   // end acc liveness before re-init

    // Layer 3: K=64, B from LDS — reuses the same accumulator registers
    #pragma unroll
    for (int nt = 0; nt < 4; ++nt) acc[nt] = f32x4{0, 0, 0, 0};
    #pragma unroll
    for (int kk = 0; kk < 2; ++kk) {
        FragH au;
        au.q = *(const uint4*)(hw + row * 72 + kk * 32 + kgrp * 8);
        #pragma unroll
        for (int nt = 0; nt < 4; ++nt) {
            FragH bu;
            bu.q = *(const uint4*)(sW23 + 4096 + (kk * 4 + nt) * 512 + lane * 8);
            acc[nt] = __builtin_amdgcn_mfma_f32_16x16x32_f16(au.v, bu.v, acc[nt], 0, 0, 0);
        }
    }

    // ---------- Layer 4: 64 -> 1, fp32 VALU + 16-lane reduce ----------------
    float part[4] = {0.f, 0.f, 0.f, 0.f};
    #pragma unroll
    for (int nt = 0; nt < 4; ++nt) {
        float bb  = sBias[64 + nt * 16 + row];
        float w4v = sBias[128 + nt * 16 + row];
        #pragma unroll
        for (int r = 0; r < 4; ++r) {
            float h = fmaxf(acc[nt][r] + bb, 0.0f);
            part[r] += h * w4v;
        }
    }
    #pragma unroll
    for (int r = 0; r < 4; ++r) {
        #pragma unroll
        for (int off = 1; off < 16; off <<= 1)
            part[r] += __shfl_xor(part[r], off);
    }
    if (row == 0) {
        float bias4 = sBias[192];
        float4 o;
        o.x = part[0] + bias4; o.y = part[1] + bias4;
        o.z = part[2] + bias4; o.w = part[3] + bias4;
        *(float4*)(out + ptbase + kgrp * 4) = o;
    }
}

// ---------------------------------------------------------------------------
extern "C" void kernel_launch(void* const* d_in, const int* in_sizes, int n_in,
                              void* d_out, int out_size, void* d_ws, size_t ws_size,
                              hipStream_t stream) {
    const float* planes = (const float*)d_in[0];
    const float* coords = (const float*)d_in[1];
    const float* W1 = (const float*)d_in[2];
    const float* b1 = (const float*)d_in[3];
    const float* W2 = (const float*)d_in[4];
    const float* b2 = (const float*)d_in[5];
    const float* W3 = (const float*)d_in[6];
    const float* b3 = (const float*)d_in[7];
    const float* W4 = (const float*)d_in[8];
    const float* b4 = (const float*)d_in[9];
    float* out = (float*)d_out;

    // Workspace: planesW fp16 (3,145,728 B) | wpack fp16 (16,384 B)
    unsigned short* planesW = (unsigned short*)d_ws;
    unsigned short* wpack   = (unsigned short*)((char*)d_ws + 3145728);

    hipLaunchKernelGGL(precompute_planesW, dim3(NB * 3 * HWDIM), dim3(256), 0, stream,
                       planes, W1, planesW);
    hipLaunchKernelGGL(pack_weights23, dim3(32), dim3(256), 0, stream,
                       W2, W3, wpack);

    int nblocks = NPTS / 128;   // 8192
    hipLaunchKernelGGL(fused_kernel, dim3(nblocks), dim3(512), 0, stream,
                       planesW, coords, wpack, b1, b2, b3, W4, b4, out);
}

// Round 16
// 89.304 us; speedup vs baseline: 2.2842x; 1.5027x over previous
//
#include <hip/hip_runtime.h>
#include <hip/hip_bf16.h>
#include <stdint.h>

// Problem constants
#define MPTS  524288      // M per batch
#define NB    2           // N
#define CCH   80          // C
#define HWDIM 64          // H = W
#define HID   64
#define NPTS  (NB * MPTS) // 2^20

typedef _Float16 f16x2 __attribute__((ext_vector_type(2)));
typedef _Float16 f16x8 __attribute__((ext_vector_type(8)));
typedef float    f32x4 __attribute__((ext_vector_type(4)));

union FragH { uint4 q; f16x8 v; f16x2 h2[4]; unsigned d[4]; _Float16 h[8]; };
union PkU   { f16x2 v; unsigned u; };

// v_pk_fma_f16: acc.lo += a.lo*b.lo ; acc.hi += a.hi*b.hi  (1 VALU op, 2 MACs)
__device__ __forceinline__ void pk_fma(unsigned& acc, unsigned a, unsigned b) {
    asm volatile("v_pk_fma_f16 %0, %1, %2, %0" : "+v"(acc) : "v"(a), "v"(b));
}
__device__ __forceinline__ unsigned pk_relu(unsigned a) {
    unsigned r;
    asm volatile("v_pk_max_f16 %0, %1, %2" : "=v"(r) : "v"(a), "v"(0u));
    return r;
}
// Splat lo/hi fp16 of a u32 into both halves (v_perm_b32, exact bit copy).
__device__ __forceinline__ unsigned splat_lo(unsigned w) {
    return __builtin_amdgcn_perm(w, w, 0x05040504u);   // bytes (1,0,1,0)
}
__device__ __forceinline__ unsigned splat_hi(unsigned w) {
    return __builtin_amdgcn_perm(w, w, 0x07060706u);   // bytes (3,2,3,2)
}

// ---------------------------------------------------------------------------
// Pre-kernel: planesW[np][y][x][64] fp16 = texel(80ch fp32) @ W1_p(80x64).
__global__ void precompute_planesW(const float* __restrict__ planes,
                                   const float* __restrict__ W1,
                                   unsigned short* __restrict__ planesW) {
    __shared__ float tA[CCH * 64];   // [c][px]
    __shared__ float tW[CCH * 64];   // [c][nn]
    int b  = blockIdx.x;
    int np = b >> 6, y = b & 63;
    int p  = np % 3;
    int t  = threadIdx.x;
    for (int i = t; i < CCH * 64; i += 256) {
        int c = i >> 6, x = i & 63;
        tA[i] = planes[((size_t)np * CCH + c) * 4096 + y * 64 + x];
        tW[i] = W1[(p * CCH + c) * HID + x];
    }
    __syncthreads();
    int px = t >> 2;
    int n0 = (t & 3) * 16;
    float acc[16];
    #pragma unroll
    for (int i = 0; i < 16; ++i) acc[i] = 0.0f;
    for (int c = 0; c < CCH; ++c) {
        float a = tA[c * 64 + px];
        #pragma unroll
        for (int i = 0; i < 16; ++i) acc[i] += a * tW[c * 64 + n0 + i];
    }
    unsigned short* dst = planesW + (((size_t)np * 4096) + y * 64 + px) * HID + n0;
    #pragma unroll
    for (int i = 0; i < 16; ++i) {
        union { _Float16 h; unsigned short u; } cv;
        cv.h = (_Float16)acc[i];
        dst[i] = cv.u;
    }
}

// ---------------------------------------------------------------------------
// Pre-kernel: W2, W3 (64x64) fp16 MFMA B-fragment order (proven layout).
__global__ void pack_weights23(const float* __restrict__ W2,
                               const float* __restrict__ W3,
                               unsigned short* __restrict__ wpack) {
    int e = blockIdx.x * 256 + threadIdx.x;   // 0..8191
    const float* W = (e < 4096) ? W2 : W3;
    int q  = e & 4095;
    int j  = q & 7;
    int l  = (q >> 3) & 63;
    int nt = (q >> 9) & 3;
    int kb = q >> 11;
    int k  = kb * 32 + ((l >> 4) << 3) + j;
    int nn = nt * 16 + (l & 15);
    union { _Float16 h; unsigned short u; } cv;
    cv.h = (_Float16)W[k * HID + nn];
    wpack[e] = cv.u;
}

// ---------------------------------------------------------------------------
// Main fused kernel: 512 threads = 8 waves, 128 points per block.
// Compact sSet -> LDS 40448 B -> 4 blocks/CU (LDS-bound). launch_bounds
// (512,6): VGPR cap ~85 (r12-proven no-spill) — occupancy comes from LDS.
__global__ __launch_bounds__(512, 6) void fused_kernel(
        const unsigned short* __restrict__ planesW,
        const float* __restrict__ coords,
        const unsigned short* __restrict__ wpack,
        const float* __restrict__ b1, const float* __restrict__ b2,
        const float* __restrict__ b3, const float* __restrict__ W4,
        const float* __restrict__ b4, float* __restrict__ out) {

    __shared__ __align__(16) unsigned short sH[8 * 16 * 72]; // 18432 B
    __shared__ unsigned sOff[128][3];                        // 1536 B: byte-off + flags
    __shared__ unsigned sWgt[128][3][2];                     // 3072 B: {w00,w01},{w10,w11} fp16 pairs
    __shared__ __align__(16) unsigned short sW23[8192];      // 16384 B
    __shared__ float sBias[200];                             // 800 B

    int t    = threadIdx.x;
    int wave = t >> 6, lane = t & 63;
    int ptbase = blockIdx.x * 128 + wave * 16;

    unsigned short* hw = sH + wave * (16 * 72);
    _Float16* hwh = (_Float16*)hw;

    // ---------- Stage W2/W3 fragments + biases into LDS --------------------
    {
        const uint4* g = (const uint4*)wpack;
        uint4* s = (uint4*)sW23;
        s[t]       = g[t];          // 1024 uint4 over 512 threads
        s[t + 512] = g[t + 512];
        if (t < 64)        sBias[t] = b2[t];
        else if (t < 128)  sBias[t] = b3[t - 64];
        else if (t < 192)  sBias[t] = W4[t - 128];
        else if (t == 192) sBias[192] = b4[0];
    }

    // ---------- Sub-phase A: per-point bilinear setup, compact records -----
    if (t < 384) {
        int i  = t & 127;                    // local point
        int p  = t >> 7;                     // plane
        int mypt = blockIdx.x * 128 + i;
        int n    = mypt >> 19;               // MPTS = 2^19
        const float* cp = coords + (size_t)mypt * 3;
        float c0 = cp[0], c1 = cp[1], c2 = cp[2];
        float gx = (p == 2) ? c2 : c0;       // p0:(x,y) p1:(x,z) p2:(z,y)
        float gy = (p == 1) ? c2 : c1;
        float fx = (gx + 1.0f) * 32.0f - 0.5f;
        float fy = (gy + 1.0f) * 32.0f - 0.5f;
        float xf = floorf(fx), yf = floorf(fy);
        float wx = fx - xf,    wy = fy - yf;
        int x0 = (int)xf, y0 = (int)yf, x1 = x0 + 1, y1 = y0 + 1;
        float vx0 = (x0 >= 0 && x0 < 64) ? 1.0f : 0.0f;
        float vx1 = (x1 >= 0 && x1 < 64) ? 1.0f : 0.0f;
        float vy0 = (y0 >= 0 && y0 < 64) ? 1.0f : 0.0f;
        float vy1 = (y1 >= 0 && y1 < 64) ? 1.0f : 0.0f;
        int cx0 = min(max(x0, 0), 63), cx1 = min(max(x1, 0), 63);
        int cy0 = min(max(y0, 0), 63), cy1 = min(max(y1, 0), 63);
        _Float16 h00 = (_Float16)((1.0f - wx) * (1.0f - wy) * vx0 * vy0);
        _Float16 h01 = (_Float16)(wx * (1.0f - wy) * vx1 * vy0);
        _Float16 h10 = (_Float16)((1.0f - wx) * wy * vx0 * vy1);
        _Float16 h11 = (_Float16)(wx * wy * vx1 * vy1);
        int base = (n * 3 + p) * 4096;
        unsigned o00b = (unsigned)(((base + (cy0 << 6) + cx0) * HID) * 2); // bytes, <2^22
        unsigned offv = o00b
                      | ((cx1 > cx0) ? (1u << 30) : 0u)
                      | ((cy1 > cy0) ? (1u << 31) : 0u);
        PkU p01; p01.v = f16x2{h00, h01};
        PkU p23; p23.v = f16x2{h10, h11};
        sOff[i][p]    = offv;
        sWgt[i][p][0] = p01.u;
        sWgt[i][p][1] = p23.u;
    }
    __syncthreads();   // the ONLY block-wide barrier

    // ---------- Sub-phase B: gather + layer-1 accumulate (pk_fma) ----------
    {
        int sub = lane & 7;                  // 8-dim octet
        int ptg = lane >> 3;                 // point group

        unsigned bp0, bp1, bp2, bp3;
        {
            const float4* bpp = (const float4*)(b1 + sub * 8);
            float4 v0 = bpp[0], v1 = bpp[1];
            PkU pk;
            pk.v = f16x2{(_Float16)v0.x, (_Float16)v0.y}; bp0 = pk.u;
            pk.v = f16x2{(_Float16)v0.z, (_Float16)v0.w}; bp1 = pk.u;
            pk.v = f16x2{(_Float16)v1.x, (_Float16)v1.y}; bp2 = pk.u;
            pk.v = f16x2{(_Float16)v1.z, (_Float16)v1.w}; bp3 = pk.u;
        }
        const char* pwB = (const char*)planesW + sub * 16;

        auto do_round = [&](int pt) {
            int pl = wave * 16 + pt;
            unsigned ovA = sOff[pl][0], ovB = sOff[pl][1], ovC = sOff[pl][2];
            unsigned wpA0 = sWgt[pl][0][0], wpA1 = sWgt[pl][0][1];
            unsigned wpB0 = sWgt[pl][1][0], wpB1 = sWgt[pl][1][1];
            unsigned wpC0 = sWgt[pl][2][0], wpC1 = sWgt[pl][2][1];

            #define RECON(OV, O00, O01, O10, O11)                                 \
                unsigned O00 = (OV) & 0x00FFFFFFu;                                \
                unsigned O01 = O00 + (((OV) >> 30) & 1u ? 128u : 0u);             \
                unsigned dY_##O00 = ((OV) >> 31) ? 8192u : 0u;                    \
                unsigned O10 = O00 + dY_##O00;                                    \
                unsigned O11 = O01 + dY_##O00;
            RECON(ovA, oA0, oA1, oA2, oA3)
            RECON(ovB, oB0, oB1, oB2, oB3)
            RECON(ovC, oC0, oC1, oC2, oC3)
            #undef RECON

            FragH u0, u1, u2, u3, u4, u5, u6, u7, u8, u9, u10, u11;
            u0.q  = *(const uint4*)(pwB + oA0);
            u1.q  = *(const uint4*)(pwB + oA1);
            u2.q  = *(const uint4*)(pwB + oA2);
            u3.q  = *(const uint4*)(pwB + oA3);
            u4.q  = *(const uint4*)(pwB + oB0);
            u5.q  = *(const uint4*)(pwB + oB1);
            u6.q  = *(const uint4*)(pwB + oB2);
            u7.q  = *(const uint4*)(pwB + oB3);
            u8.q  = *(const uint4*)(pwB + oC0);
            u9.q  = *(const uint4*)(pwB + oC1);
            u10.q = *(const uint4*)(pwB + oC2);
            u11.q = *(const uint4*)(pwB + oC3);

            unsigned a0 = bp0, a1 = bp1, a2 = bp2, a3 = bp3;

            #define TEXEL(T, WB_) { pk_fma(a0, T.d[0], WB_); pk_fma(a1, T.d[1], WB_); \
                                    pk_fma(a2, T.d[2], WB_); pk_fma(a3, T.d[3], WB_); }
            TEXEL(u0,  splat_lo(wpA0)) TEXEL(u1,  splat_hi(wpA0))
            TEXEL(u2,  splat_lo(wpA1)) TEXEL(u3,  splat_hi(wpA1))
            TEXEL(u4,  splat_lo(wpB0)) TEXEL(u5,  splat_hi(wpB0))
            TEXEL(u6,  splat_lo(wpB1)) TEXEL(u7,  splat_hi(wpB1))
            TEXEL(u8,  splat_lo(wpC0)) TEXEL(u9,  splat_hi(wpC0))
            TEXEL(u10, splat_lo(wpC1)) TEXEL(u11, splat_hi(wpC1))
            #undef TEXEL

            uint4 hv;
            hv.x = pk_relu(a0); hv.y = pk_relu(a1);
            hv.z = pk_relu(a2); hv.w = pk_relu(a3);
            *(uint4*)(hwh + pt * 72 + sub * 8) = hv;
        };
        do_round(ptg);
        do_round(8 + ptg);
    }
    // No block barrier: H tile is wave-private; compiler orders LDS hazards.

    // ---------- Layers 2 & 3 share ONE 16-AGPR accumulator -----------------
    int row  = lane & 15;
    int kgrp = lane >> 4;
    f32x4 acc[4];

    // Layer 2: K=64, A from LDS, B from LDS
    #pragma unroll
    for (int nt = 0; nt < 4; ++nt) acc[nt] = f32x4{0, 0, 0, 0};
    #pragma unroll
    for (int kk = 0; kk < 2; ++kk) {
        FragH au;
        au.q = *(const uint4*)(hw + row * 72 + kk * 32 + kgrp * 8);
        #pragma unroll
        for (int nt = 0; nt < 4; ++nt) {
            FragH bu;
            bu.q = *(const uint4*)(sW23 + (kk * 4 + nt) * 512 + lane * 8);
            acc[nt] = __builtin_amdgcn_mfma_f32_16x16x32_f16(au.v, bu.v, acc[nt], 0, 0, 0);
        }
    }

    // Epilogue 2 (biases from LDS; wave-private tile, no block barrier)
    #pragma unroll
    for (int nt = 0; nt < 4; ++nt) {
        float bb = sBias[nt * 16 + row];
        #pragma unroll
        for (int r = 0; r < 4; ++r) {
            float h = fmaxf(acc[nt][r] + bb, 0.0f);
            hwh[(kgrp * 4 + r) * 72 + nt * 16 + row] = (_Float16)h;
        }
    }
    __builtin_amdgcn_sched_barrier(0);   // end acc liveness before re-init

    // Layer 3: K=64, B from LDS — reuses the same accumulator registers
    #pragma unroll
    for (int nt = 0; nt < 4; ++nt) acc[nt] = f32x4{0, 0, 0, 0};
    #pragma unroll
    for (int kk = 0; kk < 2; ++kk) {
        FragH au;
        au.q = *(const uint4*)(hw + row * 72 + kk * 32 + kgrp * 8);
        #pragma unroll
        for (int nt = 0; nt < 4; ++nt) {
            FragH bu;
            bu.q = *(const uint4*)(sW23 + 4096 + (kk * 4 + nt) * 512 + lane * 8);
            acc[nt] = __builtin_amdgcn_mfma_f32_16x16x32_f16(au.v, bu.v, acc[nt], 0, 0, 0);
        }
    }

    // ---------- Layer 4: 64 -> 1, fp32 VALU + 16-lane reduce ----------------
    float part[4] = {0.f, 0.f, 0.f, 0.f};
    #pragma unroll
    for (int nt = 0; nt < 4; ++nt) {
        float bb  = sBias[64 + nt * 16 + row];
        float w4v = sBias[128 + nt * 16 + row];
        #pragma unroll
        for (int r = 0; r < 4; ++r) {
            float h = fmaxf(acc[nt][r] + bb, 0.0f);
            part[r] += h * w4v;
        }
    }
    #pragma unroll
    for (int r = 0; r < 4; ++r) {
        #pragma unroll
        for (int off = 1; off < 16; off <<= 1)
            part[r] += __shfl_xor(part[r], off);
    }
    if (row == 0) {
        float bias4 = sBias[192];
        float4 o;
        o.x = part[0] + bias4; o.y = part[1] + bias4;
        o.z = part[2] + bias4; o.w = part[3] + bias4;
        *(float4*)(out + ptbase + kgrp * 4) = o;
    }
}

// ---------------------------------------------------------------------------
extern "C" void kernel_launch(void* const* d_in, const int* in_sizes, int n_in,
                              void* d_out, int out_size, void* d_ws, size_t ws_size,
                              hipStream_t stream) {
    const float* planes = (const float*)d_in[0];
    const float* coords = (const float*)d_in[1];
    const float* W1 = (const float*)d_in[2];
    const float* b1 = (const float*)d_in[3];
    const float* W2 = (const float*)d_in[4];
    const float* b2 = (const float*)d_in[5];
    const float* W3 = (const float*)d_in[6];
    const float* b3 = (const float*)d_in[7];
    const float* W4 = (const float*)d_in[8];
    const float* b4 = (const float*)d_in[9];
    float* out = (float*)d_out;

    // Workspace: planesW fp16 (3,145,728 B) | wpack fp16 (16,384 B)
    unsigned short* planesW = (unsigned short*)d_ws;
    unsigned short* wpack   = (unsigned short*)((char*)d_ws + 3145728);

    hipLaunchKernelGGL(precompute_planesW, dim3(NB * 3 * HWDIM), dim3(256), 0, stream,
                       planes, W1, planesW);
    hipLaunchKernelGGL(pack_weights23, dim3(32), dim3(256), 0, stream,
                       W2, W3, wpack);

    int nblocks = NPTS / 128;   // 8192
    hipLaunchKernelGGL(fused_kernel, dim3(nblocks), dim3(512), 0, stream,
                       planesW, coords, wpack, b1, b2, b3, W4, b4, out);
}

// Round 17
// 89.159 us; speedup vs baseline: 2.2879x; 1.0016x over previous
//
#include <hip/hip_runtime.h>
#include <hip/hip_bf16.h>
#include <stdint.h>

// Problem constants
#define MPTS  524288      // M per batch
#define NB    2           // N
#define CCH   80          // C
#define HWDIM 64          // H = W
#define HID   64
#define NPTS  (NB * MPTS) // 2^20

typedef _Float16 f16x2 __attribute__((ext_vector_type(2)));
typedef _Float16 f16x8 __attribute__((ext_vector_type(8)));
typedef float    f32x4 __attribute__((ext_vector_type(4)));

union FragH { uint4 q; f16x8 v; f16x2 h2[4]; unsigned d[4]; _Float16 h[8]; };
union PkU   { f16x2 v; unsigned u; };

// v_pk_fma_f16 with op_sel splat of the weight operand (src1):
//   _lo: both result halves use w.lo   _hi: both use w.hi
// (replaces the separate v_perm splat — same bits, zero extra VALU)
__device__ __forceinline__ void pk_fma_lo(unsigned& acc, unsigned a, unsigned w) {
    asm volatile("v_pk_fma_f16 %0, %1, %2, %0 op_sel:[0,0,0] op_sel_hi:[1,0,1]"
                 : "+v"(acc) : "v"(a), "v"(w));
}
__device__ __forceinline__ void pk_fma_hi(unsigned& acc, unsigned a, unsigned w) {
    asm volatile("v_pk_fma_f16 %0, %1, %2, %0 op_sel:[0,1,0] op_sel_hi:[1,1,1]"
                 : "+v"(acc) : "v"(a), "v"(w));
}
__device__ __forceinline__ unsigned pk_relu(unsigned a) {
    unsigned r;
    asm volatile("v_pk_max_f16 %0, %1, %2" : "=v"(r) : "v"(a), "v"(0u));
    return r;
}

// ---------------------------------------------------------------------------
// Pre-kernel: planesW[np][y][x][64] fp16 = texel(80ch fp32) @ W1_p(80x64).
__global__ void precompute_planesW(const float* __restrict__ planes,
                                   const float* __restrict__ W1,
                                   unsigned short* __restrict__ planesW) {
    __shared__ float tA[CCH * 64];   // [c][px]
    __shared__ float tW[CCH * 64];   // [c][nn]
    int b  = blockIdx.x;
    int np = b >> 6, y = b & 63;
    int p  = np % 3;
    int t  = threadIdx.x;
    for (int i = t; i < CCH * 64; i += 256) {
        int c = i >> 6, x = i & 63;
        tA[i] = planes[((size_t)np * CCH + c) * 4096 + y * 64 + x];
        tW[i] = W1[(p * CCH + c) * HID + x];
    }
    __syncthreads();
    int px = t >> 2;
    int n0 = (t & 3) * 16;
    float acc[16];
    #pragma unroll
    for (int i = 0; i < 16; ++i) acc[i] = 0.0f;
    for (int c = 0; c < CCH; ++c) {
        float a = tA[c * 64 + px];
        #pragma unroll
        for (int i = 0; i < 16; ++i) acc[i] += a * tW[c * 64 + n0 + i];
    }
    unsigned short* dst = planesW + (((size_t)np * 4096) + y * 64 + px) * HID + n0;
    #pragma unroll
    for (int i = 0; i < 16; ++i) {
        union { _Float16 h; unsigned short u; } cv;
        cv.h = (_Float16)acc[i];
        dst[i] = cv.u;
    }
}

// ---------------------------------------------------------------------------
// Pre-kernel: W2, W3 (64x64) fp16 MFMA B-fragment order (proven layout).
__global__ void pack_weights23(const float* __restrict__ W2,
                               const float* __restrict__ W3,
                               unsigned short* __restrict__ wpack) {
    int e = blockIdx.x * 256 + threadIdx.x;   // 0..8191
    const float* W = (e < 4096) ? W2 : W3;
    int q  = e & 4095;
    int j  = q & 7;
    int l  = (q >> 3) & 63;
    int nt = (q >> 9) & 3;
    int kb = q >> 11;
    int k  = kb * 32 + ((l >> 4) << 3) + j;
    int nn = nt * 16 + (l & 15);
    union { _Float16 h; unsigned short u; } cv;
    cv.h = (_Float16)W[k * HID + nn];
    wpack[e] = cv.u;
}

// ---------------------------------------------------------------------------
// Main fused kernel: 512 threads = 8 waves, 128 points per block.
// Compact sSet -> LDS 40448 B -> 4 blocks/CU (LDS-bound). op_sel pk_fma
// splats + saddr-form texel loads cut ~48 VALU/wave vs r16.
__global__ __launch_bounds__(512, 6) void fused_kernel(
        const unsigned short* __restrict__ planesW,
        const float* __restrict__ coords,
        const unsigned short* __restrict__ wpack,
        const float* __restrict__ b1, const float* __restrict__ b2,
        const float* __restrict__ b3, const float* __restrict__ W4,
        const float* __restrict__ b4, float* __restrict__ out) {

    __shared__ __align__(16) unsigned short sH[8 * 16 * 72]; // 18432 B
    __shared__ unsigned sOff[128][3];                        // 1536 B: byte-off + flags
    __shared__ unsigned sWgt[128][3][2];                     // 3072 B: {w00,w01},{w10,w11} fp16 pairs
    __shared__ __align__(16) unsigned short sW23[8192];      // 16384 B
    __shared__ float sBias[200];                             // 800 B

    int t    = threadIdx.x;
    int wave = t >> 6, lane = t & 63;
    int ptbase = blockIdx.x * 128 + wave * 16;

    unsigned short* hw = sH + wave * (16 * 72);
    _Float16* hwh = (_Float16*)hw;

    // ---------- Stage W2/W3 fragments + biases into LDS --------------------
    {
        const uint4* g = (const uint4*)wpack;
        uint4* s = (uint4*)sW23;
        s[t]       = g[t];          // 1024 uint4 over 512 threads
        s[t + 512] = g[t + 512];
        if (t < 64)        sBias[t] = b2[t];
        else if (t < 128)  sBias[t] = b3[t - 64];
        else if (t < 192)  sBias[t] = W4[t - 128];
        else if (t == 192) sBias[192] = b4[0];
    }

    // ---------- Sub-phase A: per-point bilinear setup, compact records -----
    if (t < 384) {
        int i  = t & 127;                    // local point
        int p  = t >> 7;                     // plane
        int mypt = blockIdx.x * 128 + i;
        int n    = mypt >> 19;               // MPTS = 2^19
        const float* cp = coords + (size_t)mypt * 3;
        float c0 = cp[0], c1 = cp[1], c2 = cp[2];
        float gx = (p == 2) ? c2 : c0;       // p0:(x,y) p1:(x,z) p2:(z,y)
        float gy = (p == 1) ? c2 : c1;
        float fx = (gx + 1.0f) * 32.0f - 0.5f;
        float fy = (gy + 1.0f) * 32.0f - 0.5f;
        float xf = floorf(fx), yf = floorf(fy);
        float wx = fx - xf,    wy = fy - yf;
        int x0 = (int)xf, y0 = (int)yf, x1 = x0 + 1, y1 = y0 + 1;
        float vx0 = (x0 >= 0 && x0 < 64) ? 1.0f : 0.0f;
        float vx1 = (x1 >= 0 && x1 < 64) ? 1.0f : 0.0f;
        float vy0 = (y0 >= 0 && y0 < 64) ? 1.0f : 0.0f;
        float vy1 = (y1 >= 0 && y1 < 64) ? 1.0f : 0.0f;
        int cx0 = min(max(x0, 0), 63), cx1 = min(max(x1, 0), 63);
        int cy0 = min(max(y0, 0), 63), cy1 = min(max(y1, 0), 63);
        _Float16 h00 = (_Float16)((1.0f - wx) * (1.0f - wy) * vx0 * vy0);
        _Float16 h01 = (_Float16)(wx * (1.0f - wy) * vx1 * vy0);
        _Float16 h10 = (_Float16)((1.0f - wx) * wy * vx0 * vy1);
        _Float16 h11 = (_Float16)(wx * wy * vx1 * vy1);
        int base = (n * 3 + p) * 4096;
        unsigned o00b = (unsigned)(((base + (cy0 << 6) + cx0) * HID) * 2); // bytes, <2^22
        unsigned offv = o00b
                      | ((cx1 > cx0) ? (1u << 30) : 0u)
                      | ((cy1 > cy0) ? (1u << 31) : 0u);
        PkU p01; p01.v = f16x2{h00, h01};
        PkU p23; p23.v = f16x2{h10, h11};
        sOff[i][p]    = offv;
        sWgt[i][p][0] = p01.u;
        sWgt[i][p][1] = p23.u;
    }
    __syncthreads();   // the ONLY block-wide barrier

    // ---------- Sub-phase B: gather + layer-1 accumulate (pk_fma) ----------
    {
        int sub = lane & 7;                  // 8-dim octet
        int ptg = lane >> 3;                 // point group

        unsigned bp0, bp1, bp2, bp3;
        {
            const float4* bpp = (const float4*)(b1 + sub * 8);
            float4 v0 = bpp[0], v1 = bpp[1];
            PkU pk;
            pk.v = f16x2{(_Float16)v0.x, (_Float16)v0.y}; bp0 = pk.u;
            pk.v = f16x2{(_Float16)v0.z, (_Float16)v0.w}; bp1 = pk.u;
            pk.v = f16x2{(_Float16)v1.x, (_Float16)v1.y}; bp2 = pk.u;
            pk.v = f16x2{(_Float16)v1.z, (_Float16)v1.w}; bp3 = pk.u;
        }
        const char* pwB = (const char*)planesW;    // UNIFORM base (saddr form)
        unsigned subB = (unsigned)(sub * 16);      // folded into 32-bit voffset

        auto do_round = [&](int pt) {
            int pl = wave * 16 + pt;
            unsigned ovA = sOff[pl][0], ovB = sOff[pl][1], ovC = sOff[pl][2];
            unsigned wpA0 = sWgt[pl][0][0], wpA1 = sWgt[pl][0][1];
            unsigned wpB0 = sWgt[pl][1][0], wpB1 = sWgt[pl][1][1];
            unsigned wpC0 = sWgt[pl][2][0], wpC1 = sWgt[pl][2][1];

            #define RECON(OV, O00, O01, O10, O11)                                 \
                unsigned O00 = ((OV) & 0x00FFFFFFu) + subB;                       \
                unsigned O01 = O00 + (((OV) >> 30) & 1u ? 128u : 0u);             \
                unsigned dY_##O00 = ((OV) >> 31) ? 8192u : 0u;                    \
                unsigned O10 = O00 + dY_##O00;                                    \
                unsigned O11 = O01 + dY_##O00;
            RECON(ovA, oA0, oA1, oA2, oA3)
            RECON(ovB, oB0, oB1, oB2, oB3)
            RECON(ovC, oC0, oC1, oC2, oC3)
            #undef RECON

            FragH u0, u1, u2, u3, u4, u5, u6, u7, u8, u9, u10, u11;
            u0.q  = *(const uint4*)(pwB + oA0);
            u1.q  = *(const uint4*)(pwB + oA1);
            u2.q  = *(const uint4*)(pwB + oA2);
            u3.q  = *(const uint4*)(pwB + oA3);
            u4.q  = *(const uint4*)(pwB + oB0);
            u5.q  = *(const uint4*)(pwB + oB1);
            u6.q  = *(const uint4*)(pwB + oB2);
            u7.q  = *(const uint4*)(pwB + oB3);
            u8.q  = *(const uint4*)(pwB + oC0);
            u9.q  = *(const uint4*)(pwB + oC1);
            u10.q = *(const uint4*)(pwB + oC2);
            u11.q = *(const uint4*)(pwB + oC3);

            unsigned a0 = bp0, a1 = bp1, a2 = bp2, a3 = bp3;

            // op_sel splat inside the pk_fma itself — no separate v_perm.
            #define TEXEL_LO(T, WP) { pk_fma_lo(a0, T.d[0], WP); pk_fma_lo(a1, T.d[1], WP); \
                                      pk_fma_lo(a2, T.d[2], WP); pk_fma_lo(a3, T.d[3], WP); }
            #define TEXEL_HI(T, WP) { pk_fma_hi(a0, T.d[0], WP); pk_fma_hi(a1, T.d[1], WP); \
                                      pk_fma_hi(a2, T.d[2], WP); pk_fma_hi(a3, T.d[3], WP); }
            TEXEL_LO(u0,  wpA0) TEXEL_HI(u1,  wpA0)
            TEXEL_LO(u2,  wpA1) TEXEL_HI(u3,  wpA1)
            TEXEL_LO(u4,  wpB0) TEXEL_HI(u5,  wpB0)
            TEXEL_LO(u6,  wpB1) TEXEL_HI(u7,  wpB1)
            TEXEL_LO(u8,  wpC0) TEXEL_HI(u9,  wpC0)
            TEXEL_LO(u10, wpC1) TEXEL_HI(u11, wpC1)
            #undef TEXEL_LO
            #undef TEXEL_HI

            uint4 hv;
            hv.x = pk_relu(a0); hv.y = pk_relu(a1);
            hv.z = pk_relu(a2); hv.w = pk_relu(a3);
            *(uint4*)(hwh + pt * 72 + sub * 8) = hv;
        };
        do_round(ptg);
        do_round(8 + ptg);
    }
    // No block barrier: H tile is wave-private; compiler orders LDS hazards.

    // ---------- Layers 2 & 3 share ONE 16-AGPR accumulator -----------------
    int row  = lane & 15;
    int kgrp = lane >> 4;
    f32x4 acc[4];

    // Layer 2: K=64, A from LDS, B from LDS
    #pragma unroll
    for (int nt = 0; nt < 4; ++nt) acc[nt] = f32x4{0, 0, 0, 0};
    #pragma unroll
    for (int kk = 0; kk < 2; ++kk) {
        FragH au;
        au.q = *(const uint4*)(hw + row * 72 + kk * 32 + kgrp * 8);
        #pragma unroll
        for (int nt = 0; nt < 4; ++nt) {
            FragH bu;
            bu.q = *(const uint4*)(sW23 + (kk * 4 + nt) * 512 + lane * 8);
            acc[nt] = __builtin_amdgcn_mfma_f32_16x16x32_f16(au.v, bu.v, acc[nt], 0, 0, 0);
        }
    }

    // Epilogue 2 (biases from LDS; wave-private tile, no block barrier)
    #pragma unroll
    for (int nt = 0; nt < 4; ++nt) {
        float bb = sBias[nt * 16 + row];
        #pragma unroll
        for (int r = 0; r < 4; ++r) {
            float h = fmaxf(acc[nt][r] + bb, 0.0f);
            hwh[(kgrp * 4 + r) * 72 + nt * 16 + row] = (_Float16)h;
        }
    }
    __builtin_amdgcn_sched_barrier(0);   // end acc liveness before re-init

    // Layer 3: K=64, B from LDS — reuses the same accumulator registers
    #pragma unroll
    for (int nt = 0; nt < 4; ++nt) acc[nt] = f32x4{0, 0, 0, 0};
    #pragma unroll
    for (int kk = 0; kk < 2; ++kk) {
        FragH au;
        au.q = *(const uint4*)(hw + row * 72 + kk * 32 + kgrp * 8);
        #pragma unroll
        for (int nt = 0; nt < 4; ++nt) {
            FragH bu;
            bu.q = *(const uint4*)(sW23 + 4096 + (kk * 4 + nt) * 512 + lane * 8);
            acc[nt] = __builtin_amdgcn_mfma_f32_16x16x32_f16(au.v, bu.v, acc[nt], 0, 0, 0);
        }
    }

    // ---------- Layer 4: 64 -> 1, fp32 VALU + 16-lane reduce ----------------
    float part[4] = {0.f, 0.f, 0.f, 0.f};
    #pragma unroll
    for (int nt = 0; nt < 4; ++nt) {
        float bb  = sBias[64 + nt * 16 + row];
        float w4v = sBias[128 + nt * 16 + row];
        #pragma unroll
        for (int r = 0; r < 4; ++r) {
            float h = fmaxf(acc[nt][r] + bb, 0.0f);
            part[r] += h * w4v;
        }
    }
    #pragma unroll
    for (int r = 0; r < 4; ++r) {
        #pragma unroll
        for (int off = 1; off < 16; off <<= 1)
            part[r] += __shfl_xor(part[r], off);
    }
    if (row == 0) {
        float bias4 = sBias[192];
        float4 o;
        o.x = part[0] + bias4; o.y = part[1] + bias4;
        o.z = part[2] + bias4; o.w = part[3] + bias4;
        *(float4*)(out + ptbase + kgrp * 4) = o;
    }
}

// ---------------------------------------------------------------------------
extern "C" void kernel_launch(void* const* d_in, const int* in_sizes, int n_in,
                              void* d_out, int out_size, void* d_ws, size_t ws_size,
                              hipStream_t stream) {
    const float* planes = (const float*)d_in[0];
    const float* coords = (const float*)d_in[1];
    const float* W1 = (const float*)d_in[2];
    const float* b1 = (const float*)d_in[3];
    const float* W2 = (const float*)d_in[4];
    const float* b2 = (const float*)d_in[5];
    const float* W3 = (const float*)d_in[6];
    const float* b3 = (const float*)d_in[7];
    const float* W4 = (const float*)d_in[8];
    const float* b4 = (const float*)d_in[9];
    float* out = (float*)d_out;

    // Workspace: planesW fp16 (3,145,728 B) | wpack fp16 (16,384 B)
    unsigned short* planesW = (unsigned short*)d_ws;
    unsigned short* wpack   = (unsigned short*)((char*)d_ws + 3145728);

    hipLaunchKernelGGL(precompute_planesW, dim3(NB * 3 * HWDIM), dim3(256), 0, stream,
                       planes, W1, planesW);
    hipLaunchKernelGGL(pack_weights23, dim3(32), dim3(256), 0, stream,
                       W2, W3, wpack);

    int nblocks = NPTS / 128;   // 8192
    hipLaunchKernelGGL(fused_kernel, dim3(nblocks), dim3(512), 0, stream,
                       planesW, coords, wpack, b1, b2, b3, W4, b4, out);
}

// Round 18
// 87.983 us; speedup vs baseline: 2.3185x; 1.0134x over previous
//
#include <hip/hip_runtime.h>
#include <hip/hip_bf16.h>
#include <stdint.h>

// Problem constants
#define MPTS  524288      // M per batch
#define NB    2           // N
#define CCH   80          // C
#define HWDIM 64          // H = W
#define HID   64
#define NPTS  (NB * MPTS) // 2^20

typedef _Float16 f16x2 __attribute__((ext_vector_type(2)));
typedef _Float16 f16x8 __attribute__((ext_vector_type(8)));
typedef float    f32x4 __attribute__((ext_vector_type(4)));

union FragH { uint4 q; f16x8 v; f16x2 h2[4]; unsigned d[4]; _Float16 h[8]; };
union PkU   { f16x2 v; unsigned u; };

// v_pk_fma_f16 with op_sel splat of the weight operand (src1).
__device__ __forceinline__ void pk_fma_lo(unsigned& acc, unsigned a, unsigned w) {
    asm volatile("v_pk_fma_f16 %0, %1, %2, %0 op_sel:[0,0,0] op_sel_hi:[1,0,1]"
                 : "+v"(acc) : "v"(a), "v"(w));
}
__device__ __forceinline__ void pk_fma_hi(unsigned& acc, unsigned a, unsigned w) {
    asm volatile("v_pk_fma_f16 %0, %1, %2, %0 op_sel:[0,1,0] op_sel_hi:[1,1,1]"
                 : "+v"(acc) : "v"(a), "v"(w));
}
__device__ __forceinline__ unsigned pk_relu(unsigned a) {
    unsigned r;
    asm volatile("v_pk_max_f16 %0, %1, %2" : "=v"(r) : "v"(a), "v"(0u));
    return r;
}

// ---------------------------------------------------------------------------
// Pre-kernel: planesW[np][y][x][64] fp16 = texel(80ch fp32) @ W1_p(80x64).
__global__ void precompute_planesW(const float* __restrict__ planes,
                                   const float* __restrict__ W1,
                                   unsigned short* __restrict__ planesW) {
    __shared__ float tA[CCH * 64];   // [c][px]
    __shared__ float tW[CCH * 64];   // [c][nn]
    int b  = blockIdx.x;
    int np = b >> 6, y = b & 63;
    int p  = np % 3;
    int t  = threadIdx.x;
    for (int i = t; i < CCH * 64; i += 256) {
        int c = i >> 6, x = i & 63;
        tA[i] = planes[((size_t)np * CCH + c) * 4096 + y * 64 + x];
        tW[i] = W1[(p * CCH + c) * HID + x];
    }
    __syncthreads();
    int px = t >> 2;
    int n0 = (t & 3) * 16;
    float acc[16];
    #pragma unroll
    for (int i = 0; i < 16; ++i) acc[i] = 0.0f;
    for (int c = 0; c < CCH; ++c) {
        float a = tA[c * 64 + px];
        #pragma unroll
        for (int i = 0; i < 16; ++i) acc[i] += a * tW[c * 64 + n0 + i];
    }
    unsigned short* dst = planesW + (((size_t)np * 4096) + y * 64 + px) * HID + n0;
    #pragma unroll
    for (int i = 0; i < 16; ++i) {
        union { _Float16 h; unsigned short u; } cv;
        cv.h = (_Float16)acc[i];
        dst[i] = cv.u;
    }
}

// ---------------------------------------------------------------------------
// Pre-kernel: W2, W3 (64x64) fp16 MFMA fragment order (UNCHANGED layout —
// the same packing serves as the A-operand since A/B lane maps mirror).
__global__ void pack_weights23(const float* __restrict__ W2,
                               const float* __restrict__ W3,
                               unsigned short* __restrict__ wpack) {
    int e = blockIdx.x * 256 + threadIdx.x;   // 0..8191
    const float* W = (e < 4096) ? W2 : W3;
    int q  = e & 4095;
    int j  = q & 7;
    int l  = (q >> 3) & 63;
    int nt = (q >> 9) & 3;
    int kb = q >> 11;
    int k  = kb * 32 + ((l >> 4) << 3) + j;
    int nn = nt * 16 + (l & 15);
    union { _Float16 h; unsigned short u; } cv;
    cv.h = (_Float16)W[k * HID + nn];
    wpack[e] = cv.u;
}

// ---------------------------------------------------------------------------
// Main fused kernel: 512 threads = 8 waves, 128 points per block.
// MLP layers use SWAPPED MFMA operands: D = W_frag · H_frag  ->  C holds
// (row=dim, col=pt): 4 contiguous dims/lane -> b64 epilogue writes and a
// 2-shuffle layer-4 reduce (LDS-pipe diet vs 16 b16 writes + 16 shuffles).
__global__ __launch_bounds__(512, 6) void fused_kernel(
        const unsigned short* __restrict__ planesW,
        const float* __restrict__ coords,
        const unsigned short* __restrict__ wpack,
        const float* __restrict__ b1, const float* __restrict__ b2,
        const float* __restrict__ b3, const float* __restrict__ W4,
        const float* __restrict__ b4, float* __restrict__ out) {

    __shared__ __align__(16) unsigned short sH[8 * 16 * 72]; // 18432 B
    __shared__ unsigned sOff[128][3];                        // 1536 B
    __shared__ unsigned sWgt[128][3][2];                     // 3072 B
    __shared__ __align__(16) unsigned short sW23[8192];      // 16384 B
    __shared__ __align__(16) float sBias[200];               // b2[0:64) b3[64:128) W4[128:192) b4[192]

    int t    = threadIdx.x;
    int wave = t >> 6, lane = t & 63;
    int ptbase = blockIdx.x * 128 + wave * 16;

    unsigned short* hw = sH + wave * (16 * 72);
    _Float16* hwh = (_Float16*)hw;

    // ---------- Stage W2/W3 fragments + biases into LDS --------------------
    {
        const uint4* g = (const uint4*)wpack;
        uint4* s = (uint4*)sW23;
        s[t]       = g[t];
        s[t + 512] = g[t + 512];
        if (t < 64)        sBias[t] = b2[t];
        else if (t < 128)  sBias[t] = b3[t - 64];
        else if (t < 192)  sBias[t] = W4[t - 128];
        else if (t == 192) sBias[192] = b4[0];
    }

    // ---------- Sub-phase A: per-point bilinear setup, compact records -----
    if (t < 384) {
        int i  = t & 127;                    // local point
        int p  = t >> 7;                     // plane
        int mypt = blockIdx.x * 128 + i;
        int n    = mypt >> 19;               // MPTS = 2^19
        const float* cp = coords + (size_t)mypt * 3;
        float c0 = cp[0], c1 = cp[1], c2 = cp[2];
        float gx = (p == 2) ? c2 : c0;       // p0:(x,y) p1:(x,z) p2:(z,y)
        float gy = (p == 1) ? c2 : c1;
        float fx = (gx + 1.0f) * 32.0f - 0.5f;
        float fy = (gy + 1.0f) * 32.0f - 0.5f;
        float xf = floorf(fx), yf = floorf(fy);
        float wx = fx - xf,    wy = fy - yf;
        int x0 = (int)xf, y0 = (int)yf, x1 = x0 + 1, y1 = y0 + 1;
        float vx0 = (x0 >= 0 && x0 < 64) ? 1.0f : 0.0f;
        float vx1 = (x1 >= 0 && x1 < 64) ? 1.0f : 0.0f;
        float vy0 = (y0 >= 0 && y0 < 64) ? 1.0f : 0.0f;
        float vy1 = (y1 >= 0 && y1 < 64) ? 1.0f : 0.0f;
        int cx0 = min(max(x0, 0), 63), cx1 = min(max(x1, 0), 63);
        int cy0 = min(max(y0, 0), 63), cy1 = min(max(y1, 0), 63);
        _Float16 h00 = (_Float16)((1.0f - wx) * (1.0f - wy) * vx0 * vy0);
        _Float16 h01 = (_Float16)(wx * (1.0f - wy) * vx1 * vy0);
        _Float16 h10 = (_Float16)((1.0f - wx) * wy * vx0 * vy1);
        _Float16 h11 = (_Float16)(wx * wy * vx1 * vy1);
        int base = (n * 3 + p) * 4096;
        unsigned o00b = (unsigned)(((base + (cy0 << 6) + cx0) * HID) * 2); // bytes
        unsigned offv = o00b
                      | ((cx1 > cx0) ? (1u << 30) : 0u)
                      | ((cy1 > cy0) ? (1u << 31) : 0u);
        PkU p01; p01.v = f16x2{h00, h01};
        PkU p23; p23.v = f16x2{h10, h11};
        sOff[i][p]    = offv;
        sWgt[i][p][0] = p01.u;
        sWgt[i][p][1] = p23.u;
    }
    __syncthreads();   // the ONLY block-wide barrier

    // ---------- Sub-phase B: gather + layer-1 accumulate (pk_fma) ----------
    {
        int sub = lane & 7;                  // 8-dim octet
        int ptg = lane >> 3;                 // point group

        unsigned bp0, bp1, bp2, bp3;
        {
            const float4* bpp = (const float4*)(b1 + sub * 8);
            float4 v0 = bpp[0], v1 = bpp[1];
            PkU pk;
            pk.v = f16x2{(_Float16)v0.x, (_Float16)v0.y}; bp0 = pk.u;
            pk.v = f16x2{(_Float16)v0.z, (_Float16)v0.w}; bp1 = pk.u;
            pk.v = f16x2{(_Float16)v1.x, (_Float16)v1.y}; bp2 = pk.u;
            pk.v = f16x2{(_Float16)v1.z, (_Float16)v1.w}; bp3 = pk.u;
        }
        const char* pwB = (const char*)planesW;    // uniform base (saddr form)
        unsigned subB = (unsigned)(sub * 16);      // folded into 32-bit voffset

        auto do_round = [&](int pt) {
            int pl = wave * 16 + pt;
            unsigned ovA = sOff[pl][0], ovB = sOff[pl][1], ovC = sOff[pl][2];
            unsigned wpA0 = sWgt[pl][0][0], wpA1 = sWgt[pl][0][1];
            unsigned wpB0 = sWgt[pl][1][0], wpB1 = sWgt[pl][1][1];
            unsigned wpC0 = sWgt[pl][2][0], wpC1 = sWgt[pl][2][1];

            #define RECON(OV, O00, O01, O10, O11)                                 \
                unsigned O00 = ((OV) & 0x00FFFFFFu) + subB;                       \
                unsigned O01 = O00 + (((OV) >> 30) & 1u ? 128u : 0u);             \
                unsigned dY_##O00 = ((OV) >> 31) ? 8192u : 0u;                    \
                unsigned O10 = O00 + dY_##O00;                                    \
                unsigned O11 = O01 + dY_##O00;
            RECON(ovA, oA0, oA1, oA2, oA3)
            RECON(ovB, oB0, oB1, oB2, oB3)
            RECON(ovC, oC0, oC1, oC2, oC3)
            #undef RECON

            FragH u0, u1, u2, u3, u4, u5, u6, u7, u8, u9, u10, u11;
            u0.q  = *(const uint4*)(pwB + oA0);
            u1.q  = *(const uint4*)(pwB + oA1);
            u2.q  = *(const uint4*)(pwB + oA2);
            u3.q  = *(const uint4*)(pwB + oA3);
            u4.q  = *(const uint4*)(pwB + oB0);
            u5.q  = *(const uint4*)(pwB + oB1);
            u6.q  = *(const uint4*)(pwB + oB2);
            u7.q  = *(const uint4*)(pwB + oB3);
            u8.q  = *(const uint4*)(pwB + oC0);
            u9.q  = *(const uint4*)(pwB + oC1);
            u10.q = *(const uint4*)(pwB + oC2);
            u11.q = *(const uint4*)(pwB + oC3);

            unsigned a0 = bp0, a1 = bp1, a2 = bp2, a3 = bp3;

            #define TEXEL_LO(T, WP) { pk_fma_lo(a0, T.d[0], WP); pk_fma_lo(a1, T.d[1], WP); \
                                      pk_fma_lo(a2, T.d[2], WP); pk_fma_lo(a3, T.d[3], WP); }
            #define TEXEL_HI(T, WP) { pk_fma_hi(a0, T.d[0], WP); pk_fma_hi(a1, T.d[1], WP); \
                                      pk_fma_hi(a2, T.d[2], WP); pk_fma_hi(a3, T.d[3], WP); }
            TEXEL_LO(u0,  wpA0) TEXEL_HI(u1,  wpA0)
            TEXEL_LO(u2,  wpA1) TEXEL_HI(u3,  wpA1)
            TEXEL_LO(u4,  wpB0) TEXEL_HI(u5,  wpB0)
            TEXEL_LO(u6,  wpB1) TEXEL_HI(u7,  wpB1)
            TEXEL_LO(u8,  wpC0) TEXEL_HI(u9,  wpC0)
            TEXEL_LO(u10, wpC1) TEXEL_HI(u11, wpC1)
            #undef TEXEL_LO
            #undef TEXEL_HI

            uint4 hv;
            hv.x = pk_relu(a0); hv.y = pk_relu(a1);
            hv.z = pk_relu(a2); hv.w = pk_relu(a3);
            *(uint4*)(hwh + pt * 72 + sub * 8) = hv;
        };
        do_round(ptg);
        do_round(8 + ptg);
    }
    // No block barrier: H tile is wave-private; compiler orders LDS hazards.

    // ---------- Layers 2 & 3: SWAPPED operands (D = W_frag · H_frag) -------
    // C layout: row = dim = mt*16 + kgrp*4 + r (4 contiguous dims per lane),
    //           col = pt  = lane&15.
    int row  = lane & 15;    // point index in wave tile
    int kgrp = lane >> 4;
    f32x4 acc[4];

    // Layer 2
    #pragma unroll
    for (int mt = 0; mt < 4; ++mt) acc[mt] = f32x4{0, 0, 0, 0};
    #pragma unroll
    for (int kk = 0; kk < 2; ++kk) {
        FragH hu;
        hu.q = *(const uint4*)(hw + row * 72 + kk * 32 + kgrp * 8);   // H fragment
        #pragma unroll
        for (int mt = 0; mt < 4; ++mt) {
            FragH wu;
            wu.q = *(const uint4*)(sW23 + (kk * 4 + mt) * 512 + lane * 8);
            acc[mt] = __builtin_amdgcn_mfma_f32_16x16x32_f16(wu.v, hu.v, acc[mt], 0, 0, 0);
        }
    }

    // Epilogue 2: 4 contiguous dims per lane -> one b64 write per mt.
    #pragma unroll
    for (int mt = 0; mt < 4; ++mt) {
        const float4 bb4 = *(const float4*)&sBias[mt * 16 + kgrp * 4];
        _Float16 h0 = (_Float16)fmaxf(acc[mt][0] + bb4.x, 0.0f);
        _Float16 h1 = (_Float16)fmaxf(acc[mt][1] + bb4.y, 0.0f);
        _Float16 h2 = (_Float16)fmaxf(acc[mt][2] + bb4.z, 0.0f);
        _Float16 h3 = (_Float16)fmaxf(acc[mt][3] + bb4.w, 0.0f);
        PkU lo; lo.v = f16x2{h0, h1};
        PkU hi; hi.v = f16x2{h2, h3};
        uint2 wv; wv.x = lo.u; wv.y = hi.u;
        *(uint2*)(hwh + row * 72 + mt * 16 + kgrp * 4) = wv;
    }
    __builtin_amdgcn_sched_barrier(0);   // end acc liveness before re-init

    // Layer 3 (same swapped form, same accumulator registers)
    #pragma unroll
    for (int mt = 0; mt < 4; ++mt) acc[mt] = f32x4{0, 0, 0, 0};
    #pragma unroll
    for (int kk = 0; kk < 2; ++kk) {
        FragH hu;
        hu.q = *(const uint4*)(hw + row * 72 + kk * 32 + kgrp * 8);
        #pragma unroll
        for (int mt = 0; mt < 4; ++mt) {
            FragH wu;
            wu.q = *(const uint4*)(sW23 + 4096 + (kk * 4 + mt) * 512 + lane * 8);
            acc[mt] = __builtin_amdgcn_mfma_f32_16x16x32_f16(wu.v, hu.v, acc[mt], 0, 0, 0);
        }
    }

    // ---------- Layer 4: per-lane 16-dim partial + 2-shuffle reduce --------
    float part = 0.0f;
    #pragma unroll
    for (int mt = 0; mt < 4; ++mt) {
        const float4 b3v = *(const float4*)&sBias[64 + mt * 16 + kgrp * 4];
        const float4 w4v = *(const float4*)&sBias[128 + mt * 16 + kgrp * 4];
        part += fmaxf(acc[mt][0] + b3v.x, 0.0f) * w4v.x;
        part += fmaxf(acc[mt][1] + b3v.y, 0.0f) * w4v.y;
        part += fmaxf(acc[mt][2] + b3v.z, 0.0f) * w4v.z;
        part += fmaxf(acc[mt][3] + b3v.w, 0.0f) * w4v.w;
    }
    part += __shfl_xor(part, 16);
    part += __shfl_xor(part, 32);
    if (lane < 16) out[ptbase + lane] = part + sBias[192];
}

// ---------------------------------------------------------------------------
extern "C" void kernel_launch(void* const* d_in, const int* in_sizes, int n_in,
                              void* d_out, int out_size, void* d_ws, size_t ws_size,
                              hipStream_t stream) {
    const float* planes = (const float*)d_in[0];
    const float* coords = (const float*)d_in[1];
    const float* W1 = (const float*)d_in[2];
    const float* b1 = (const float*)d_in[3];
    const float* W2 = (const float*)d_in[4];
    const float* b2 = (const float*)d_in[5];
    const float* W3 = (const float*)d_in[6];
    const float* b3 = (const float*)d_in[7];
    const float* W4 = (const float*)d_in[8];
    const float* b4 = (const float*)d_in[9];
    float* out = (float*)d_out;

    // Workspace: planesW fp16 (3,145,728 B) | wpack fp16 (16,384 B)
    unsigned short* planesW = (unsigned short*)d_ws;
    unsigned short* wpack   = (unsigned short*)((char*)d_ws + 3145728);

    hipLaunchKernelGGL(precompute_planesW, dim3(NB * 3 * HWDIM), dim3(256), 0, stream,
                       planes, W1, planesW);
    hipLaunchKernelGGL(pack_weights23, dim3(32), dim3(256), 0, stream,
                       W2, W3, wpack);

    int nblocks = NPTS / 128;   // 8192
    hipLaunchKernelGGL(fused_kernel, dim3(nblocks), dim3(512), 0, stream,
                       planesW, coords, wpack, b1, b2, b3, W4, b4, out);
}